// Round 5
// baseline (22822.186 us; speedup 1.0000x reference)
//
#include <hip/hip_runtime.h>

#define BB 32
#define TT 512
#define INW 256
#define HH 1024
#define OUTW 256
#define XSTRIDE 1032  // hlds row stride in ushorts (2064 B, 16B-aligned)
// 3H = 3072

typedef __attribute__((ext_vector_type(8))) short short8;
typedef __attribute__((ext_vector_type(4))) float floatx4;
typedef __attribute__((ext_vector_type(4))) int intx4;

union U4 { unsigned int u[4]; intx4 v; };

__device__ __forceinline__ unsigned short f2bf(float f) {
    unsigned int u = __float_as_uint(f);
    u = (u + 0x7fffu + ((u >> 16) & 1u)) >> 16;
    return (unsigned short)u;
}
__device__ __forceinline__ float bf2f(unsigned short h) {
    return __uint_as_float(((unsigned int)h) << 16);
}

__global__ void cast_f32_bf16(const float* __restrict__ src,
                              unsigned short* __restrict__ dst, int n) {
    int i = blockIdx.x * blockDim.x + threadIdx.x;
    int stride = gridDim.x * blockDim.x;
    for (; i < n; i += stride) dst[i] = f2bf(src[i]);
}

// C_bf16[M x 3072] = X_bf16[M x K] @ W_bf16[3072 x K]^T + bias_f32
template <int K>
__global__ __launch_bounds__(256) void gemm_gx(const unsigned short* __restrict__ X,
                                               const unsigned short* __restrict__ W,
                                               const float* __restrict__ bias,
                                               unsigned short* __restrict__ Cout) {
    __shared__ __align__(16) unsigned short As[64 * 40];
    __shared__ __align__(16) unsigned short Bs[64 * 40];
    int bid = blockIdx.x;
    int tn = bid % 48, tm = bid / 48;
    int tid = threadIdx.x;
    int lane = tid & 63, wv = tid >> 6;
    int wm = wv >> 1, wn = wv & 1;
    int l15 = lane & 15, q = lane >> 4;
    floatx4 acc[2][2] = {};
    int r = tid >> 2, kq = (tid & 3) * 8;
    const int NK = K / 32;
    for (int kk = 0; kk < NK; ++kk) {
        int k0 = kk * 32;
        *(short8*)&As[r * 40 + kq] = *(const short8*)&X[(size_t)(tm * 64 + r) * K + k0 + kq];
        *(short8*)&Bs[r * 40 + kq] = *(const short8*)&W[(size_t)(tn * 64 + r) * K + k0 + kq];
        __syncthreads();
        short8 a0 = *(const short8*)&As[(wm * 32 + l15) * 40 + q * 8];
        short8 a1 = *(const short8*)&As[(wm * 32 + 16 + l15) * 40 + q * 8];
        short8 b0 = *(const short8*)&Bs[(wn * 32 + l15) * 40 + q * 8];
        short8 b1 = *(const short8*)&Bs[(wn * 32 + 16 + l15) * 40 + q * 8];
        acc[0][0] = __builtin_amdgcn_mfma_f32_16x16x32_bf16(a0, b0, acc[0][0], 0, 0, 0);
        acc[0][1] = __builtin_amdgcn_mfma_f32_16x16x32_bf16(a0, b1, acc[0][1], 0, 0, 0);
        acc[1][0] = __builtin_amdgcn_mfma_f32_16x16x32_bf16(a1, b0, acc[1][0], 0, 0, 0);
        acc[1][1] = __builtin_amdgcn_mfma_f32_16x16x32_bf16(a1, b1, acc[1][1], 0, 0, 0);
        __syncthreads();
    }
    for (int mi = 0; mi < 2; ++mi)
        for (int ni = 0; ni < 2; ++ni) {
            int col = tn * 64 + wn * 32 + ni * 16 + l15;
            float bv = bias[col];
            int row0 = tm * 64 + wm * 32 + mi * 16 + q * 4;
            for (int rr = 0; rr < 4; ++rr) {
                Cout[(size_t)(row0 + rr) * 3072 + col] = f2bf(acc[mi][ni][rr] + bv);
            }
        }
}

#define MFMA_STEP(s)                                                            \
    {                                                                           \
        int k = (s)*32 + q * 8;                                                 \
        short8 a0 = *(const short8*)&hlds[l15 * XSTRIDE + k];                   \
        short8 a1 = *(const short8*)&hlds[(16 + l15) * XSTRIDE + k];            \
        short8 b0 = *(const short8*)&wp0[k];                                    \
        short8 b1 = *(const short8*)&wp1[k];                                    \
        short8 b2 = *(const short8*)&wp2[k];                                    \
        acc[0][0] = __builtin_amdgcn_mfma_f32_16x16x32_bf16(a0, b0, acc[0][0], 0, 0, 0); \
        acc[0][1] = __builtin_amdgcn_mfma_f32_16x16x32_bf16(a0, b1, acc[0][1], 0, 0, 0); \
        acc[0][2] = __builtin_amdgcn_mfma_f32_16x16x32_bf16(a0, b2, acc[0][2], 0, 0, 0); \
        acc[1][0] = __builtin_amdgcn_mfma_f32_16x16x32_bf16(a1, b0, acc[1][0], 0, 0, 0); \
        acc[1][1] = __builtin_amdgcn_mfma_f32_16x16x32_bf16(a1, b1, acc[1][1], 0, 0, 0); \
        acc[1][2] = __builtin_amdgcn_mfma_f32_16x16x32_bf16(a1, b2, acc[1][2], 0, 0, 0); \
    }

// Persistent GRU recurrence: 16 blocks x 256 threads.
// Block owns 64 j's (4 waves x 16 j), each wave runs the FULL K=1024 -> the
// (r,z,n) for a (b,j) land in one lane's 3 accumulators: gate phase is
// lane-local, fp32 h in registers, no cross-wave reduction.
// h16T is b-major [2][32][1024] bf16; exports are full 128B lines via LDS
// slice. All cross-block traffic uses R2/R3-proven agent-scope atomics.
__global__ __launch_bounds__(256) void gru_rec(const unsigned short* __restrict__ gx,
                                               const unsigned short* __restrict__ whh,
                                               const float* __restrict__ bhh,
                                               unsigned short* __restrict__ h16T,
                                               unsigned short* __restrict__ out0,
                                               float* __restrict__ hn_out,
                                               unsigned int* __restrict__ flags) {
    __shared__ __align__(16) unsigned short hlds[32 * XSTRIDE];
    __shared__ __align__(16) unsigned short slice[32 * 72];
    const int bid = blockIdx.x, tid = threadIdx.x;
    const int lane = tid & 63, wv = tid >> 6;
    const int l15 = lane & 15, q = lane >> 4;
    const int j0 = bid * 64;
    const int j = j0 + wv * 16 + l15;  // lane's j-column
    const unsigned short* wp0 = whh + (size_t)j * HH;
    const unsigned short* wp1 = whh + (size_t)(1024 + j) * HH;
    const unsigned short* wp2 = whh + (size_t)(2048 + j) * HH;
    const float bR = bhh[j], bZ = bhh[1024 + j], bN = bhh[2048 + j];
    // gx row bases for this lane's 8 b-values (C-layout: b = mi*16 + q*4 + r)
    const unsigned short* gxb[8];
#pragma unroll
    for (int mi = 0; mi < 2; ++mi)
#pragma unroll
        for (int r = 0; r < 4; ++r)
            gxb[mi * 4 + r] = gx + (size_t)(mi * 16 + q * 4 + r) * TT * 3072 + j;
    float hpriv[8] = {};
    const int crow = tid >> 3, cseg = tid & 7;  // copy/export mapping

    for (int t = 0; t < TT; ++t) {
        // gate inputs for this step (latency hidden behind copy+MFMA)
        unsigned short cx[3][8];
#pragma unroll
        for (int i = 0; i < 8; ++i) {
            const unsigned short* p = gxb[i] + (size_t)t * 3072;
            cx[0][i] = p[0];
            cx[1][i] = p[1024];
            cx[2][i] = p[2048];
        }

        floatx4 acc[2][3] = {};
        if (t > 0) {
            // ---- wait for h(t) from all 16 blocks
            unsigned int target = (unsigned int)t;
            while (true) {
                unsigned int v = __hip_atomic_load(flags + (lane & 15), __ATOMIC_RELAXED,
                                                   __HIP_MEMORY_SCOPE_AGENT);
                if (__all((int)(v >= target))) break;
                __builtin_amdgcn_s_sleep(1);
            }
            // ---- copy h (64KB, agent loads) -> hlds, 2-stage pipelined vs MFMA
            const unsigned short* hc = h16T + (size_t)(t & 1) * (BB * HH);
            const unsigned int* s0 =
                (const unsigned int*)(hc + (size_t)crow * HH + cseg * 64);
            const unsigned int* s1 = s0 + 256;  // +512 ushorts = second k-half
            unsigned int va[32], vb[32];
#pragma unroll
            for (int i = 0; i < 32; ++i)
                va[i] = __hip_atomic_load(s0 + i, __ATOMIC_RELAXED,
                                          __HIP_MEMORY_SCOPE_AGENT);
#pragma unroll
            for (int i = 0; i < 32; ++i)
                vb[i] = __hip_atomic_load(s1 + i, __ATOMIC_RELAXED,
                                          __HIP_MEMORY_SCOPE_AGENT);
            {
                unsigned short* d = &hlds[crow * XSTRIDE + cseg * 64];
#pragma unroll
                for (int g2 = 0; g2 < 8; ++g2) {
                    U4 u;
                    u.u[0] = va[g2 * 4];
                    u.u[1] = va[g2 * 4 + 1];
                    u.u[2] = va[g2 * 4 + 2];
                    u.u[3] = va[g2 * 4 + 3];
                    *(intx4*)(d + g2 * 8) = u.v;
                }
            }
            __syncthreads();
#pragma unroll 4
            for (int s = 0; s < 16; ++s) MFMA_STEP(s)
            {
                unsigned short* d = &hlds[crow * XSTRIDE + 512 + cseg * 64];
#pragma unroll
                for (int g2 = 0; g2 < 8; ++g2) {
                    U4 u;
                    u.u[0] = vb[g2 * 4];
                    u.u[1] = vb[g2 * 4 + 1];
                    u.u[2] = vb[g2 * 4 + 2];
                    u.u[3] = vb[g2 * 4 + 3];
                    *(intx4*)(d + g2 * 8) = u.v;
                }
            }
            __syncthreads();
#pragma unroll 4
            for (int s = 16; s < 32; ++s) MFMA_STEP(s)
        }
        // else t==0: h=0 -> gh=0, acc stays zero

        // ---- gate phase: fully lane-local
#pragma unroll
        for (int mi = 0; mi < 2; ++mi)
#pragma unroll
            for (int r = 0; r < 4; ++r) {
                int i = mi * 4 + r;
                float gr = acc[mi][0][r] + bR;
                float gz = acc[mi][1][r] + bZ;
                float gn = acc[mi][2][r] + bN;
                float xr = bf2f(cx[0][i]);
                float xz = bf2f(cx[1][i]);
                float xn = bf2f(cx[2][i]);
                float rg = 1.f / (1.f + __expf(-(xr + gr)));
                float zg = 1.f / (1.f + __expf(-(xz + gz)));
                float ng = tanhf(xn + rg * gn);
                float hnew = (1.f - zg) * ng + zg * hpriv[i];
                hpriv[i] = hnew;
                slice[(mi * 16 + q * 4 + r) * 72 + wv * 16 + l15] = f2bf(hnew);
            }
        __syncthreads();

        // ---- export h(t+1): full 128B lines, agent scope
        U4 sv;
        sv.v = *(const intx4*)&slice[crow * 72 + cseg * 8];
        {
            unsigned short* hb = h16T + (size_t)((t + 1) & 1) * (BB * HH);
            unsigned int* dst = (unsigned int*)(hb + (size_t)crow * HH + j0 + cseg * 8);
#pragma unroll
            for (int d2 = 0; d2 < 4; ++d2)
                __hip_atomic_store(dst + d2, sv.u[d2], __ATOMIC_RELAXED,
                                   __HIP_MEMORY_SCOPE_AGENT);
        }
        asm volatile("s_waitcnt vmcnt(0)" ::: "memory");
        __syncthreads();
        if (tid == 0)
            __hip_atomic_store(flags + bid, (unsigned int)(t + 1), __ATOMIC_RELAXED,
                               __HIP_MEMORY_SCOPE_AGENT);

        // ---- off-critical-path stores
        if (out0)
            *(intx4*)&out0[((size_t)crow * TT + t) * HH + j0 + cseg * 8] = sv.v;
        if (t == TT - 1) {
            float* hf = hn_out + (size_t)crow * HH + j0 + cseg * 8;
            floatx4 f0 = {bf2f((unsigned short)(sv.u[0] & 0xffff)),
                          bf2f((unsigned short)(sv.u[0] >> 16)),
                          bf2f((unsigned short)(sv.u[1] & 0xffff)),
                          bf2f((unsigned short)(sv.u[1] >> 16))};
            floatx4 f1 = {bf2f((unsigned short)(sv.u[2] & 0xffff)),
                          bf2f((unsigned short)(sv.u[2] >> 16)),
                          bf2f((unsigned short)(sv.u[3] & 0xffff)),
                          bf2f((unsigned short)(sv.u[3] >> 16))};
            *(floatx4*)(hf) = f0;
            *(floatx4*)(hf + 4) = f1;
        }
    }
}

__global__ void fc_out(const float* __restrict__ h1, const float* __restrict__ fcw,
                       const float* __restrict__ fcb, float* __restrict__ out) {
    int b = blockIdx.x, o = threadIdx.x;  // 32 x 256
    const float* hb = h1 + b * HH;
    const float* wr = fcw + o * HH;
    float acc = fcb[o];
    for (int k = 0; k < HH; k += 4) {
        acc += hb[k] * wr[k] + hb[k + 1] * wr[k + 1] + hb[k + 2] * wr[k + 2] +
               hb[k + 3] * wr[k + 3];
    }
    out[b * OUTW + o] = 1.f / (1.f + expf(-acc));
}

extern "C" void kernel_launch(void* const* d_in, const int* in_sizes, int n_in,
                              void* d_out, int out_size, void* d_ws, size_t ws_size,
                              hipStream_t stream) {
    (void)in_sizes; (void)n_in; (void)out_size; (void)ws_size;
    const float* input = (const float*)d_in[0];
    const float* w_ih0 = (const float*)d_in[1];
    const float* w_hh0 = (const float*)d_in[2];
    const float* b_ih0 = (const float*)d_in[3];
    const float* b_hh0 = (const float*)d_in[4];
    const float* w_ih1 = (const float*)d_in[5];
    const float* w_hh1 = (const float*)d_in[6];
    const float* b_ih1 = (const float*)d_in[7];
    const float* b_hh1 = (const float*)d_in[8];
    const float* fc_w = (const float*)d_in[9];
    const float* fc_b = (const float*)d_in[10];
    float* out = (float*)d_out;

    char* ws = (char*)d_ws;
    size_t off = 0;
    auto alloc = [&](size_t bytes) {
        void* p = ws + off;
        off += (bytes + 255) & ~(size_t)255;
        return p;
    };
    unsigned int* flags = (unsigned int*)alloc(4096);  // L0: [0..16), L1: [64..80)
    unsigned short* h16T = (unsigned short*)alloc((size_t)2 * BB * HH * 2);  // 128 KB
    unsigned short* gx = (unsigned short*)alloc((size_t)16384 * 3072 * 2);
    unsigned short* out0 = (unsigned short*)alloc((size_t)16384 * 1024 * 2);
    unsigned short* in_bf = (unsigned short*)alloc((size_t)16384 * 256 * 2);
    unsigned short* wih0_bf = (unsigned short*)alloc((size_t)3072 * 256 * 2);
    unsigned short* whh0_bf = (unsigned short*)alloc((size_t)3072 * 1024 * 2);
    unsigned short* wih1_bf = (unsigned short*)alloc((size_t)3072 * 1024 * 2);
    unsigned short* whh1_bf = (unsigned short*)alloc((size_t)3072 * 1024 * 2);

    cast_f32_bf16<<<256, 256, 0, stream>>>(input, in_bf, 16384 * 256);
    cast_f32_bf16<<<64, 256, 0, stream>>>(w_ih0, wih0_bf, 3072 * 256);
    cast_f32_bf16<<<256, 256, 0, stream>>>(w_hh0, whh0_bf, 3072 * 1024);
    cast_f32_bf16<<<256, 256, 0, stream>>>(w_ih1, wih1_bf, 3072 * 1024);
    cast_f32_bf16<<<256, 256, 0, stream>>>(w_hh1, whh1_bf, 3072 * 1024);

    hipMemsetAsync(flags, 0, 4096, stream);

    // ---- layer 0 ----
    gemm_gx<256><<<12288, 256, 0, stream>>>(in_bf, wih0_bf, b_ih0, gx);
    gru_rec<<<16, 256, 0, stream>>>(gx, whh0_bf, b_hh0, h16T, out0, out + 8192, flags);

    // ---- layer 1 ----
    gemm_gx<1024><<<12288, 256, 0, stream>>>(out0, wih1_bf, b_ih1, gx);
    gru_rec<<<16, 256, 0, stream>>>(gx, whh1_bf, b_hh1, h16T,
                                    (unsigned short*)nullptr, out + 8192 + 32768,
                                    flags + 64);

    // ---- FC + sigmoid on h_last of layer 1 ----
    fc_out<<<32, 256, 0, stream>>>(out + 8192 + 32768, fc_w, fc_b, out);
}

// Round 6
// 8066.849 us; speedup vs baseline: 2.8291x; 2.8291x over previous
//
#include <hip/hip_runtime.h>

#define BB 32
#define TT 512
#define INW 256
#define HH 1024
#define OUTW 256
#define SLOT 32768  // ushorts per ring slot (32 x 1024)
// 3H = 3072

typedef __attribute__((ext_vector_type(8))) short short8;
typedef __attribute__((ext_vector_type(4))) float floatx4;

__device__ __forceinline__ unsigned short f2bf(float f) {
    unsigned int u = __float_as_uint(f);
    u = (u + 0x7fffu + ((u >> 16) & 1u)) >> 16;
    return (unsigned short)u;
}
__device__ __forceinline__ float bf2f(unsigned short h) {
    return __uint_as_float(((unsigned int)h) << 16);
}

__global__ void cast_f32_bf16(const float* __restrict__ src,
                              unsigned short* __restrict__ dst, int n) {
    int i = blockIdx.x * blockDim.x + threadIdx.x;
    int stride = gridDim.x * blockDim.x;
    for (; i < n; i += stride) dst[i] = f2bf(src[i]);
}

// C_bf16[M x 3072] = X @ W^T + bias. RING=false: X row m at X[m*K].
// RING=true: row m=(b*512+t) lives at X[((t+1)*32 + b)*1024] (h-ring layout).
template <int K, bool RING>
__global__ __launch_bounds__(256) void gemm_gx(const unsigned short* __restrict__ X,
                                               const unsigned short* __restrict__ W,
                                               const float* __restrict__ bias,
                                               unsigned short* __restrict__ Cout) {
    __shared__ __align__(16) unsigned short As[64 * 40];
    __shared__ __align__(16) unsigned short Bs[64 * 40];
    int bid = blockIdx.x;
    int tn = bid % 48, tm = bid / 48;
    int tid = threadIdx.x;
    int lane = tid & 63, wv = tid >> 6;
    int wm = wv >> 1, wn = wv & 1;
    int l15 = lane & 15, q = lane >> 4;
    floatx4 acc[2][2] = {};
    int r = tid >> 2, kq = (tid & 3) * 8;
    int m = tm * 64 + r;
    const unsigned short* xrow;
    if (RING) {
        int bb = m >> 9, t2 = m & 511;
        xrow = X + ((size_t)(t2 + 1) * 32 + bb) * 1024;
    } else {
        xrow = X + (size_t)m * K;
    }
    const unsigned short* wrow = W + (size_t)(tn * 64 + r) * K;
    const int NK = K / 32;
    for (int kk = 0; kk < NK; ++kk) {
        int k0 = kk * 32;
        *(short8*)&As[r * 40 + kq] = *(const short8*)&xrow[k0 + kq];
        *(short8*)&Bs[r * 40 + kq] = *(const short8*)&wrow[k0 + kq];
        __syncthreads();
        short8 a0 = *(const short8*)&As[(wm * 32 + l15) * 40 + q * 8];
        short8 a1 = *(const short8*)&As[(wm * 32 + 16 + l15) * 40 + q * 8];
        short8 b0 = *(const short8*)&Bs[(wn * 32 + l15) * 40 + q * 8];
        short8 b1 = *(const short8*)&Bs[(wn * 32 + 16 + l15) * 40 + q * 8];
        acc[0][0] = __builtin_amdgcn_mfma_f32_16x16x32_bf16(a0, b0, acc[0][0], 0, 0, 0);
        acc[0][1] = __builtin_amdgcn_mfma_f32_16x16x32_bf16(a0, b1, acc[0][1], 0, 0, 0);
        acc[1][0] = __builtin_amdgcn_mfma_f32_16x16x32_bf16(a1, b0, acc[1][0], 0, 0, 0);
        acc[1][1] = __builtin_amdgcn_mfma_f32_16x16x32_bf16(a1, b1, acc[1][1], 0, 0, 0);
        __syncthreads();
    }
    for (int mi = 0; mi < 2; ++mi)
        for (int ni = 0; ni < 2; ++ni) {
            int col = tn * 64 + wn * 32 + ni * 16 + l15;
            float bv = bias[col];
            int row0 = tm * 64 + wm * 32 + mi * 16 + q * 4;
            for (int rr = 0; rr < 4; ++rr) {
                Cout[(size_t)(row0 + rr) * 3072 + col] = f2bf(acc[mi][ni][rr] + bv);
            }
        }
}

// Persistent GRU recurrence, 64 blocks x 256 threads, ring-buffered h.
// Producer: agent stores (write-through to coherence point) -> vmcnt(0) ->
// syncthreads -> flags[bid]=t+1. Consumer: poll 64 flags (agent), then PLAIN
// cached loads of slot t — addresses are fresh each step, so L1/L2 cannot be
// stale; same-XCD blocks share L2 fills. No anti-dependency (ring never
// overwrites), so no back-pressure.
__global__ __launch_bounds__(256) void gru_rec(const unsigned short* __restrict__ gx,
                                               const unsigned short* __restrict__ whh,
                                               const float* __restrict__ bhh,
                                               unsigned short* __restrict__ hring,
                                               float* __restrict__ hn_out,
                                               unsigned int* __restrict__ flags) {
    __shared__ __align__(16) float red[4 * 6 * 64 * 4];
    const int bid = blockIdx.x;
    const int tid = threadIdx.x;
    const int lane = tid & 63, wv = tid >> 6;
    const int l15 = lane & 15, q = lane >> 4;
    const int j0 = bid * 16;
    const int kbase = wv * 256;
    const unsigned short* wr0 = whh + (size_t)(j0 + l15) * HH;
    const unsigned short* wr1 = whh + (size_t)(1024 + j0 + l15) * HH;
    const unsigned short* wr2 = whh + (size_t)(2048 + j0 + l15) * HH;

    // gate-phase ownership: thread -> (b, 2*jh) and (b, 2*jh+1), fixed across
    // steps so fp32 h lives in registers.
    const int b = tid & 31, jh = tid >> 5;
    const int mi = b >> 4, reg = b & 3;
    const int rbase = ((b & 15) >> 2) * 16 + 2 * jh;  // MFMA C-layout lane
    float hpriv[2] = {0.f, 0.f};
    const float bhr0 = bhh[j0 + 2 * jh], bhr1 = bhh[j0 + 2 * jh + 1];
    const float bhz0 = bhh[1024 + j0 + 2 * jh], bhz1 = bhh[1024 + j0 + 2 * jh + 1];
    const float bhn0 = bhh[2048 + j0 + 2 * jh], bhn1 = bhh[2048 + j0 + 2 * jh + 1];
    const unsigned short* gxb = gx + (size_t)b * TT * 3072 + j0 + 2 * jh;
    unsigned int pxr = *(const unsigned int*)(gxb);
    unsigned int pxz = *(const unsigned int*)(gxb + 1024);
    unsigned int pxn = *(const unsigned int*)(gxb + 2048);

    for (int t = 0; t < TT; ++t) {
        // ---- wait for h(t) from all blocks (slot t fully exported)
        if (t > 0) {
            unsigned int target = (unsigned int)t;
            while (true) {
                unsigned int v = __hip_atomic_load(flags + lane, __ATOMIC_RELAXED,
                                                   __HIP_MEMORY_SCOPE_AGENT);
                if (__all((int)(v >= target))) break;
                __builtin_amdgcn_s_sleep(1);
            }
            asm volatile("" ::: "memory");  // keep data loads below the poll
        }
        const unsigned short* hc = hring + (size_t)t * SLOT;        // slot t
        unsigned short* hn = hring + (size_t)(t + 1) * SLOT;        // slot t+1
        unsigned int cxr = pxr, cxz = pxz, cxn = pxn;

        floatx4 acc[6] = {};  // tile = mi*3 + gate
#pragma unroll
        for (int s = 0; s < 8; ++s) {
            int k = kbase + s * 32 + q * 8;
            short8 a0 = *(const short8*)&hc[(size_t)l15 * HH + k];         // plain,
            short8 a1 = *(const short8*)&hc[(size_t)(16 + l15) * HH + k];  // cached
            short8 b0 = *(const short8*)&wr0[k];
            short8 b1 = *(const short8*)&wr1[k];
            short8 b2 = *(const short8*)&wr2[k];
            acc[0] = __builtin_amdgcn_mfma_f32_16x16x32_bf16(a0, b0, acc[0], 0, 0, 0);
            acc[1] = __builtin_amdgcn_mfma_f32_16x16x32_bf16(a0, b1, acc[1], 0, 0, 0);
            acc[2] = __builtin_amdgcn_mfma_f32_16x16x32_bf16(a0, b2, acc[2], 0, 0, 0);
            acc[3] = __builtin_amdgcn_mfma_f32_16x16x32_bf16(a1, b0, acc[3], 0, 0, 0);
            acc[4] = __builtin_amdgcn_mfma_f32_16x16x32_bf16(a1, b1, acc[4], 0, 0, 0);
            acc[5] = __builtin_amdgcn_mfma_f32_16x16x32_bf16(a1, b2, acc[5], 0, 0, 0);
        }
#pragma unroll
        for (int tl = 0; tl < 6; ++tl)
            *(floatx4*)&red[((wv * 6 + tl) * 64 + lane) * 4] = acc[tl];
        __syncthreads();

        float hnew[2];
#pragma unroll
        for (int i = 0; i < 2; ++i) {
            int rl = rbase + i;
            float gr = 0.f, gz = 0.f, gn = 0.f;
#pragma unroll
            for (int w = 0; w < 4; ++w) {
                gr += red[((w * 6 + mi * 3 + 0) * 64 + rl) * 4 + reg];
                gz += red[((w * 6 + mi * 3 + 1) * 64 + rl) * 4 + reg];
                gn += red[((w * 6 + mi * 3 + 2) * 64 + rl) * 4 + reg];
            }
            gr += i ? bhr1 : bhr0;
            gz += i ? bhz1 : bhz0;
            gn += i ? bhn1 : bhn0;
            float xr = bf2f((unsigned short)(i ? (cxr >> 16) : (cxr & 0xffffu)));
            float xz = bf2f((unsigned short)(i ? (cxz >> 16) : (cxz & 0xffffu)));
            float xn = bf2f((unsigned short)(i ? (cxn >> 16) : (cxn & 0xffffu)));
            float rg = 1.f / (1.f + __expf(-(xr + gr)));
            float zg = 1.f / (1.f + __expf(-(xz + gz)));
            float ng = tanhf(xn + rg * gn);
            hnew[i] = (1.f - zg) * ng + zg * hpriv[i];
            hpriv[i] = hnew[i];
        }
        unsigned int hpack =
            (unsigned int)f2bf(hnew[0]) | ((unsigned int)f2bf(hnew[1]) << 16);
        int jj = b * HH + j0 + 2 * jh;
        // release: agent store (write-through), ack, then flag
        __hip_atomic_store((unsigned int*)&hn[jj], hpack, __ATOMIC_RELAXED,
                           __HIP_MEMORY_SCOPE_AGENT);
        asm volatile("s_waitcnt vmcnt(0)" ::: "memory");
        __syncthreads();
        if (tid == 0)
            __hip_atomic_store(flags + bid, (unsigned int)(t + 1), __ATOMIC_RELAXED,
                               __HIP_MEMORY_SCOPE_AGENT);

        // off-critical-path
        if (t == TT - 1) {
            hn_out[jj] = hnew[0];
            hn_out[jj + 1] = hnew[1];
        }
        if (t + 1 < TT) {
            const unsigned short* g2 = gxb + (size_t)(t + 1) * 3072;
            pxr = *(const unsigned int*)(g2);
            pxz = *(const unsigned int*)(g2 + 1024);
            pxn = *(const unsigned int*)(g2 + 2048);
        }
    }
}

__global__ void fc_out(const unsigned short* __restrict__ h1bf,
                       const float* __restrict__ fcw, const float* __restrict__ fcb,
                       float* __restrict__ out) {
    int b = blockIdx.x, o = threadIdx.x;  // 32 x 256
    const unsigned short* hb = h1bf + (size_t)b * HH;
    const float* wr = fcw + (size_t)o * HH;
    float acc = fcb[o];
    for (int k = 0; k < HH; k += 4) {
        acc += bf2f(hb[k]) * wr[k] + bf2f(hb[k + 1]) * wr[k + 1] +
               bf2f(hb[k + 2]) * wr[k + 2] + bf2f(hb[k + 3]) * wr[k + 3];
    }
    out[b * OUTW + o] = 1.f / (1.f + expf(-acc));
}

extern "C" void kernel_launch(void* const* d_in, const int* in_sizes, int n_in,
                              void* d_out, int out_size, void* d_ws, size_t ws_size,
                              hipStream_t stream) {
    (void)in_sizes; (void)n_in; (void)out_size; (void)ws_size;
    const float* input = (const float*)d_in[0];
    const float* w_ih0 = (const float*)d_in[1];
    const float* w_hh0 = (const float*)d_in[2];
    const float* b_ih0 = (const float*)d_in[3];
    const float* b_hh0 = (const float*)d_in[4];
    const float* w_ih1 = (const float*)d_in[5];
    const float* w_hh1 = (const float*)d_in[6];
    const float* b_ih1 = (const float*)d_in[7];
    const float* b_hh1 = (const float*)d_in[8];
    const float* fc_w = (const float*)d_in[9];
    const float* fc_b = (const float*)d_in[10];
    float* out = (float*)d_out;

    char* ws = (char*)d_ws;
    size_t off = 0;
    auto alloc = [&](size_t bytes) {
        void* p = ws + off;
        off += (bytes + 255) & ~(size_t)255;
        return p;
    };
    unsigned int* flags = (unsigned int*)alloc(4096);  // L0: [0..64), L1: [64..128)
    unsigned short* ring0 = (unsigned short*)alloc((size_t)(TT + 1) * SLOT * 2);  // 33.6MB
    unsigned short* ring1 = (unsigned short*)alloc((size_t)(TT + 1) * SLOT * 2);
    unsigned short* gx = (unsigned short*)alloc((size_t)16384 * 3072 * 2);
    unsigned short* in_bf = (unsigned short*)alloc((size_t)16384 * 256 * 2);
    unsigned short* wih0_bf = (unsigned short*)alloc((size_t)3072 * 256 * 2);
    unsigned short* whh0_bf = (unsigned short*)alloc((size_t)3072 * 1024 * 2);
    unsigned short* wih1_bf = (unsigned short*)alloc((size_t)3072 * 1024 * 2);
    unsigned short* whh1_bf = (unsigned short*)alloc((size_t)3072 * 1024 * 2);

    cast_f32_bf16<<<256, 256, 0, stream>>>(input, in_bf, 16384 * 256);
    cast_f32_bf16<<<64, 256, 0, stream>>>(w_ih0, wih0_bf, 3072 * 256);
    cast_f32_bf16<<<256, 256, 0, stream>>>(w_hh0, whh0_bf, 3072 * 1024);
    cast_f32_bf16<<<256, 256, 0, stream>>>(w_ih1, wih1_bf, 3072 * 1024);
    cast_f32_bf16<<<256, 256, 0, stream>>>(w_hh1, whh1_bf, 3072 * 1024);

    hipMemsetAsync(flags, 0, 4096, stream);
    hipMemsetAsync(ring0, 0, (size_t)SLOT * 2, stream);  // h(0) = 0
    hipMemsetAsync(ring1, 0, (size_t)SLOT * 2, stream);

    // ---- layer 0 ----
    gemm_gx<256, false><<<12288, 256, 0, stream>>>(in_bf, wih0_bf, b_ih0, gx);
    gru_rec<<<64, 256, 0, stream>>>(gx, whh0_bf, b_hh0, ring0, out + 8192, flags);

    // ---- layer 1 (A-rows streamed straight from ring0) ----
    gemm_gx<1024, true><<<12288, 256, 0, stream>>>(ring0, wih1_bf, b_ih1, gx);
    gru_rec<<<64, 256, 0, stream>>>(gx, whh1_bf, b_hh1, ring1, out + 8192 + 32768,
                                    flags + 64);

    // ---- FC + sigmoid on h_last of layer 1 (ring1 slot TT) ----
    fc_out<<<32, 256, 0, stream>>>(ring1 + (size_t)TT * SLOT, fc_w, fc_b, out);
}

// Round 7
// 7113.627 us; speedup vs baseline: 3.2082x; 1.1340x over previous
//
#include <hip/hip_runtime.h>

#define BB 32
#define TT 512
#define INW 256
#define HH 1024
#define OUTW 256
#define SLOT 32768  // ushorts per ring slot (32 x 1024)
// 3H = 3072

typedef __attribute__((ext_vector_type(8))) short short8;
typedef __attribute__((ext_vector_type(4))) float floatx4;

__device__ __forceinline__ unsigned short f2bf(float f) {
    unsigned int u = __float_as_uint(f);
    u = (u + 0x7fffu + ((u >> 16) & 1u)) >> 16;
    return (unsigned short)u;
}
__device__ __forceinline__ float bf2f(unsigned short h) {
    return __uint_as_float(((unsigned int)h) << 16);
}

__global__ void cast_f32_bf16(const float* __restrict__ src,
                              unsigned short* __restrict__ dst, int n) {
    int i = blockIdx.x * blockDim.x + threadIdx.x;
    int stride = gridDim.x * blockDim.x;
    for (; i < n; i += stride) dst[i] = f2bf(src[i]);
}

// C_bf16[M x 3072] = X_bf16[M x K] @ W_bf16[3072 x K]^T + bias_f32
template <int K>
__global__ __launch_bounds__(256) void gemm_gx(const unsigned short* __restrict__ X,
                                               const unsigned short* __restrict__ W,
                                               const float* __restrict__ bias,
                                               unsigned short* __restrict__ Cout) {
    __shared__ __align__(16) unsigned short As[64 * 40];
    __shared__ __align__(16) unsigned short Bs[64 * 40];
    int bid = blockIdx.x;
    int tn = bid % 48, tm = bid / 48;
    int tid = threadIdx.x;
    int lane = tid & 63, wv = tid >> 6;
    int wm = wv >> 1, wn = wv & 1;
    int l15 = lane & 15, q = lane >> 4;
    floatx4 acc[2][2] = {};
    int r = tid >> 2, kq = (tid & 3) * 8;
    const unsigned short* xrow = X + (size_t)(tm * 64 + r) * K;
    const unsigned short* wrow = W + (size_t)(tn * 64 + r) * K;
    const int NK = K / 32;
    for (int kk = 0; kk < NK; ++kk) {
        int k0 = kk * 32;
        *(short8*)&As[r * 40 + kq] = *(const short8*)&xrow[k0 + kq];
        *(short8*)&Bs[r * 40 + kq] = *(const short8*)&wrow[k0 + kq];
        __syncthreads();
        short8 a0 = *(const short8*)&As[(wm * 32 + l15) * 40 + q * 8];
        short8 a1 = *(const short8*)&As[(wm * 32 + 16 + l15) * 40 + q * 8];
        short8 b0 = *(const short8*)&Bs[(wn * 32 + l15) * 40 + q * 8];
        short8 b1 = *(const short8*)&Bs[(wn * 32 + 16 + l15) * 40 + q * 8];
        acc[0][0] = __builtin_amdgcn_mfma_f32_16x16x32_bf16(a0, b0, acc[0][0], 0, 0, 0);
        acc[0][1] = __builtin_amdgcn_mfma_f32_16x16x32_bf16(a0, b1, acc[0][1], 0, 0, 0);
        acc[1][0] = __builtin_amdgcn_mfma_f32_16x16x32_bf16(a1, b0, acc[1][0], 0, 0, 0);
        acc[1][1] = __builtin_amdgcn_mfma_f32_16x16x32_bf16(a1, b1, acc[1][1], 0, 0, 0);
        __syncthreads();
    }
    for (int mi = 0; mi < 2; ++mi)
        for (int ni = 0; ni < 2; ++ni) {
            int col = tn * 64 + wn * 32 + ni * 16 + l15;
            float bv = bias[col];
            int row0 = tm * 64 + wm * 32 + mi * 16 + q * 4;
            for (int rr = 0; rr < 4; ++rr) {
                Cout[(size_t)(row0 + rr) * 3072 + col] = f2bf(acc[mi][ni][rr] + bv);
            }
        }
}

// Fused 2-layer persistent GRU: 128 blocks x 256 threads.
// Blocks 0-63:  layer 0, identical to R6 (gx0 stream + whh0, export ring0).
// Blocks 64-127: layer 1, one step behind: reads h0(t) = ring0 slot t+1 and
// h1(t) = ring1 slot t, computes BOTH the w_ih1 and w_hh1 matmuls on the fly
// (r,z accumulate together; n kept split), exports ring1.
// Rings are write-once per slot -> consumers use plain cached loads (fresh
// addresses can't be stale; same-XCD blocks share L2 fills); producers use
// agent stores + vmcnt(0) + per-block flag (R2..R6-proven primitives).
__global__ __launch_bounds__(256) void gru_fused(
    const unsigned short* __restrict__ gx0, const unsigned short* __restrict__ whh0,
    const float* __restrict__ bhh0, const unsigned short* __restrict__ wih1,
    const unsigned short* __restrict__ whh1, const float* __restrict__ bih1,
    const float* __restrict__ bhh1, unsigned short* __restrict__ ring0,
    unsigned short* __restrict__ ring1, float* __restrict__ hn0,
    float* __restrict__ hn1, unsigned int* __restrict__ flags) {
    __shared__ __align__(16) float red[4 * 8 * 64 * 4];
    const int bid = blockIdx.x;
    const int tid = threadIdx.x;
    const int lane = tid & 63, wv = tid >> 6;
    const int l15 = lane & 15, q = lane >> 4;
    const int kbase = wv * 256;
    const int b = tid & 31, jh = tid >> 5;
    const int mi = b >> 4, reg = b & 3;
    const int rbase = ((b & 15) >> 2) * 16 + 2 * jh;  // MFMA C-layout lane

    if (bid < 64) {
        // ================= layer 0 =================
        const int j0 = bid * 16;
        const unsigned short* wr0 = whh0 + (size_t)(j0 + l15) * HH;
        const unsigned short* wr1 = whh0 + (size_t)(1024 + j0 + l15) * HH;
        const unsigned short* wr2 = whh0 + (size_t)(2048 + j0 + l15) * HH;
        float hpriv[2] = {0.f, 0.f};
        const float bhr0 = bhh0[j0 + 2 * jh], bhr1 = bhh0[j0 + 2 * jh + 1];
        const float bhz0 = bhh0[1024 + j0 + 2 * jh], bhz1 = bhh0[1024 + j0 + 2 * jh + 1];
        const float bhn0 = bhh0[2048 + j0 + 2 * jh], bhn1 = bhh0[2048 + j0 + 2 * jh + 1];
        const unsigned short* gxb = gx0 + (size_t)b * TT * 3072 + j0 + 2 * jh;
        unsigned int pxr = *(const unsigned int*)(gxb);
        unsigned int pxz = *(const unsigned int*)(gxb + 1024);
        unsigned int pxn = *(const unsigned int*)(gxb + 2048);

        for (int t = 0; t < TT; ++t) {
            if (t > 0) {
                unsigned int target = (unsigned int)t;
                while (true) {
                    unsigned int v = __hip_atomic_load(flags + lane, __ATOMIC_RELAXED,
                                                       __HIP_MEMORY_SCOPE_AGENT);
                    if (__all((int)(v >= target))) break;
                    __builtin_amdgcn_s_sleep(1);
                }
                asm volatile("" ::: "memory");
            }
            const unsigned short* hc = ring0 + (size_t)t * SLOT;
            unsigned short* hn = ring0 + (size_t)(t + 1) * SLOT;
            unsigned int cxr = pxr, cxz = pxz, cxn = pxn;

            floatx4 acc[6] = {};
#pragma unroll
            for (int s = 0; s < 8; ++s) {
                int k = kbase + s * 32 + q * 8;
                short8 a0 = *(const short8*)&hc[(size_t)l15 * HH + k];
                short8 a1 = *(const short8*)&hc[(size_t)(16 + l15) * HH + k];
                short8 b0 = *(const short8*)&wr0[k];
                short8 b1 = *(const short8*)&wr1[k];
                short8 b2 = *(const short8*)&wr2[k];
                acc[0] = __builtin_amdgcn_mfma_f32_16x16x32_bf16(a0, b0, acc[0], 0, 0, 0);
                acc[1] = __builtin_amdgcn_mfma_f32_16x16x32_bf16(a0, b1, acc[1], 0, 0, 0);
                acc[2] = __builtin_amdgcn_mfma_f32_16x16x32_bf16(a0, b2, acc[2], 0, 0, 0);
                acc[3] = __builtin_amdgcn_mfma_f32_16x16x32_bf16(a1, b0, acc[3], 0, 0, 0);
                acc[4] = __builtin_amdgcn_mfma_f32_16x16x32_bf16(a1, b1, acc[4], 0, 0, 0);
                acc[5] = __builtin_amdgcn_mfma_f32_16x16x32_bf16(a1, b2, acc[5], 0, 0, 0);
            }
#pragma unroll
            for (int tl = 0; tl < 6; ++tl)
                *(floatx4*)&red[((wv * 6 + tl) * 64 + lane) * 4] = acc[tl];
            __syncthreads();

            float hnew[2];
#pragma unroll
            for (int i = 0; i < 2; ++i) {
                int rl = rbase + i;
                float gr = 0.f, gz = 0.f, gn = 0.f;
#pragma unroll
                for (int w = 0; w < 4; ++w) {
                    gr += red[((w * 6 + mi * 3 + 0) * 64 + rl) * 4 + reg];
                    gz += red[((w * 6 + mi * 3 + 1) * 64 + rl) * 4 + reg];
                    gn += red[((w * 6 + mi * 3 + 2) * 64 + rl) * 4 + reg];
                }
                gr += i ? bhr1 : bhr0;
                gz += i ? bhz1 : bhz0;
                gn += i ? bhn1 : bhn0;
                float xr = bf2f((unsigned short)(i ? (cxr >> 16) : (cxr & 0xffffu)));
                float xz = bf2f((unsigned short)(i ? (cxz >> 16) : (cxz & 0xffffu)));
                float xn = bf2f((unsigned short)(i ? (cxn >> 16) : (cxn & 0xffffu)));
                float rg = 1.f / (1.f + __expf(-(xr + gr)));
                float zg = 1.f / (1.f + __expf(-(xz + gz)));
                float ng = tanhf(xn + rg * gn);
                hnew[i] = (1.f - zg) * ng + zg * hpriv[i];
                hpriv[i] = hnew[i];
            }
            unsigned int hpack =
                (unsigned int)f2bf(hnew[0]) | ((unsigned int)f2bf(hnew[1]) << 16);
            int jj = b * HH + j0 + 2 * jh;
            __hip_atomic_store((unsigned int*)&hn[jj], hpack, __ATOMIC_RELAXED,
                               __HIP_MEMORY_SCOPE_AGENT);
            asm volatile("s_waitcnt vmcnt(0)" ::: "memory");
            __syncthreads();
            if (tid == 0)
                __hip_atomic_store(flags + bid, (unsigned int)(t + 1), __ATOMIC_RELAXED,
                                   __HIP_MEMORY_SCOPE_AGENT);
            if (t == TT - 1) {
                hn0[jj] = hnew[0];
                hn0[jj + 1] = hnew[1];
            }
            if (t + 1 < TT) {
                const unsigned short* g2 = gxb + (size_t)(t + 1) * 3072;
                pxr = *(const unsigned int*)(g2);
                pxz = *(const unsigned int*)(g2 + 1024);
                pxn = *(const unsigned int*)(g2 + 2048);
            }
        }
    } else {
        // ================= layer 1 (one step behind) =================
        const int b2 = bid - 64;
        const int j0 = b2 * 16;
        const unsigned short* wi0 = wih1 + (size_t)(j0 + l15) * HH;
        const unsigned short* wi1 = wih1 + (size_t)(1024 + j0 + l15) * HH;
        const unsigned short* wi2 = wih1 + (size_t)(2048 + j0 + l15) * HH;
        const unsigned short* wh0 = whh1 + (size_t)(j0 + l15) * HH;
        const unsigned short* wh1 = whh1 + (size_t)(1024 + j0 + l15) * HH;
        const unsigned short* wh2 = whh1 + (size_t)(2048 + j0 + l15) * HH;
        float hpriv[2] = {0.f, 0.f};
        // combined biases: r,z get both; n split (x-part, h-part)
        const float cR0 = bih1[j0 + 2 * jh] + bhh1[j0 + 2 * jh];
        const float cR1 = bih1[j0 + 2 * jh + 1] + bhh1[j0 + 2 * jh + 1];
        const float cZ0 = bih1[1024 + j0 + 2 * jh] + bhh1[1024 + j0 + 2 * jh];
        const float cZ1 = bih1[1024 + j0 + 2 * jh + 1] + bhh1[1024 + j0 + 2 * jh + 1];
        const float cNx0 = bih1[2048 + j0 + 2 * jh];
        const float cNx1 = bih1[2048 + j0 + 2 * jh + 1];
        const float cNh0 = bhh1[2048 + j0 + 2 * jh];
        const float cNh1 = bhh1[2048 + j0 + 2 * jh + 1];

        for (int t = 0; t < TT; ++t) {
            // need h0(t) = ring0 slot t+1 (flags0 >= t+1) and own ring1 slot t
            unsigned int tgt0 = (unsigned int)(t + 1), tgt1 = (unsigned int)t;
            while (true) {
                unsigned int v0 = __hip_atomic_load(flags + lane, __ATOMIC_RELAXED,
                                                    __HIP_MEMORY_SCOPE_AGENT);
                unsigned int v1 = __hip_atomic_load(flags + 64 + lane, __ATOMIC_RELAXED,
                                                    __HIP_MEMORY_SCOPE_AGENT);
                if (__all((int)(v0 >= tgt0 && v1 >= tgt1))) break;
                __builtin_amdgcn_s_sleep(1);
            }
            asm volatile("" ::: "memory");
            const unsigned short* x0 = ring0 + (size_t)(t + 1) * SLOT;  // h0(t)
            const unsigned short* h1c = ring1 + (size_t)t * SLOT;
            unsigned short* h1n = ring1 + (size_t)(t + 1) * SLOT;

            floatx4 acc[8] = {};  // mi*4 + {r, z, nx, nh}
#pragma unroll
            for (int s = 0; s < 8; ++s) {
                int k = kbase + s * 32 + q * 8;
                short8 xa0 = *(const short8*)&x0[(size_t)l15 * HH + k];
                short8 xa1 = *(const short8*)&x0[(size_t)(16 + l15) * HH + k];
                short8 ha0 = *(const short8*)&h1c[(size_t)l15 * HH + k];
                short8 ha1 = *(const short8*)&h1c[(size_t)(16 + l15) * HH + k];
                short8 fir = *(const short8*)&wi0[k];
                short8 fiz = *(const short8*)&wi1[k];
                short8 fin = *(const short8*)&wi2[k];
                short8 fhr = *(const short8*)&wh0[k];
                short8 fhz = *(const short8*)&wh1[k];
                short8 fhn = *(const short8*)&wh2[k];
                acc[0] = __builtin_amdgcn_mfma_f32_16x16x32_bf16(xa0, fir, acc[0], 0, 0, 0);
                acc[0] = __builtin_amdgcn_mfma_f32_16x16x32_bf16(ha0, fhr, acc[0], 0, 0, 0);
                acc[1] = __builtin_amdgcn_mfma_f32_16x16x32_bf16(xa0, fiz, acc[1], 0, 0, 0);
                acc[1] = __builtin_amdgcn_mfma_f32_16x16x32_bf16(ha0, fhz, acc[1], 0, 0, 0);
                acc[2] = __builtin_amdgcn_mfma_f32_16x16x32_bf16(xa0, fin, acc[2], 0, 0, 0);
                acc[3] = __builtin_amdgcn_mfma_f32_16x16x32_bf16(ha0, fhn, acc[3], 0, 0, 0);
                acc[4] = __builtin_amdgcn_mfma_f32_16x16x32_bf16(xa1, fir, acc[4], 0, 0, 0);
                acc[4] = __builtin_amdgcn_mfma_f32_16x16x32_bf16(ha1, fhr, acc[4], 0, 0, 0);
                acc[5] = __builtin_amdgcn_mfma_f32_16x16x32_bf16(xa1, fiz, acc[5], 0, 0, 0);
                acc[5] = __builtin_amdgcn_mfma_f32_16x16x32_bf16(ha1, fhz, acc[5], 0, 0, 0);
                acc[6] = __builtin_amdgcn_mfma_f32_16x16x32_bf16(xa1, fin, acc[6], 0, 0, 0);
                acc[7] = __builtin_amdgcn_mfma_f32_16x16x32_bf16(ha1, fhn, acc[7], 0, 0, 0);
            }
#pragma unroll
            for (int tl = 0; tl < 8; ++tl)
                *(floatx4*)&red[((wv * 8 + tl) * 64 + lane) * 4] = acc[tl];
            __syncthreads();

            float hnew[2];
#pragma unroll
            for (int i = 0; i < 2; ++i) {
                int rl = rbase + i;
                float gr = 0.f, gz = 0.f, xn = 0.f, hnp = 0.f;
#pragma unroll
                for (int w = 0; w < 4; ++w) {
                    gr += red[((w * 8 + mi * 4 + 0) * 64 + rl) * 4 + reg];
                    gz += red[((w * 8 + mi * 4 + 1) * 64 + rl) * 4 + reg];
                    xn += red[((w * 8 + mi * 4 + 2) * 64 + rl) * 4 + reg];
                    hnp += red[((w * 8 + mi * 4 + 3) * 64 + rl) * 4 + reg];
                }
                gr += i ? cR1 : cR0;
                gz += i ? cZ1 : cZ0;
                xn += i ? cNx1 : cNx0;
                hnp += i ? cNh1 : cNh0;
                float rg = 1.f / (1.f + __expf(-gr));
                float zg = 1.f / (1.f + __expf(-gz));
                float ng = tanhf(xn + rg * hnp);
                hnew[i] = (1.f - zg) * ng + zg * hpriv[i];
                hpriv[i] = hnew[i];
            }
            unsigned int hpack =
                (unsigned int)f2bf(hnew[0]) | ((unsigned int)f2bf(hnew[1]) << 16);
            int jj = b * HH + j0 + 2 * jh;
            __hip_atomic_store((unsigned int*)&h1n[jj], hpack, __ATOMIC_RELAXED,
                               __HIP_MEMORY_SCOPE_AGENT);
            asm volatile("s_waitcnt vmcnt(0)" ::: "memory");
            __syncthreads();
            if (tid == 0)
                __hip_atomic_store(flags + 64 + b2, (unsigned int)(t + 1),
                                   __ATOMIC_RELAXED, __HIP_MEMORY_SCOPE_AGENT);
            if (t == TT - 1) {
                hn1[jj] = hnew[0];
                hn1[jj + 1] = hnew[1];
            }
        }
    }
}

__global__ void fc_out(const unsigned short* __restrict__ h1bf,
                       const float* __restrict__ fcw, const float* __restrict__ fcb,
                       float* __restrict__ out) {
    int b = blockIdx.x, o = threadIdx.x;  // 32 x 256
    const unsigned short* hb = h1bf + (size_t)b * HH;
    const float* wr = fcw + (size_t)o * HH;
    float acc = fcb[o];
    for (int k = 0; k < HH; k += 4) {
        acc += bf2f(hb[k]) * wr[k] + bf2f(hb[k + 1]) * wr[k + 1] +
               bf2f(hb[k + 2]) * wr[k + 2] + bf2f(hb[k + 3]) * wr[k + 3];
    }
    out[b * OUTW + o] = 1.f / (1.f + expf(-acc));
}

extern "C" void kernel_launch(void* const* d_in, const int* in_sizes, int n_in,
                              void* d_out, int out_size, void* d_ws, size_t ws_size,
                              hipStream_t stream) {
    (void)in_sizes; (void)n_in; (void)out_size; (void)ws_size;
    const float* input = (const float*)d_in[0];
    const float* w_ih0 = (const float*)d_in[1];
    const float* w_hh0 = (const float*)d_in[2];
    const float* b_ih0 = (const float*)d_in[3];
    const float* b_hh0 = (const float*)d_in[4];
    const float* w_ih1 = (const float*)d_in[5];
    const float* w_hh1 = (const float*)d_in[6];
    const float* b_ih1 = (const float*)d_in[7];
    const float* b_hh1 = (const float*)d_in[8];
    const float* fc_w = (const float*)d_in[9];
    const float* fc_b = (const float*)d_in[10];
    float* out = (float*)d_out;

    char* ws = (char*)d_ws;
    size_t off = 0;
    auto alloc = [&](size_t bytes) {
        void* p = ws + off;
        off += (bytes + 255) & ~(size_t)255;
        return p;
    };
    unsigned int* flags = (unsigned int*)alloc(4096);  // L0: [0..64), L1: [64..128)
    unsigned short* ring0 = (unsigned short*)alloc((size_t)(TT + 1) * SLOT * 2);
    unsigned short* ring1 = (unsigned short*)alloc((size_t)(TT + 1) * SLOT * 2);
    unsigned short* gx0 = (unsigned short*)alloc((size_t)16384 * 3072 * 2);
    unsigned short* in_bf = (unsigned short*)alloc((size_t)16384 * 256 * 2);
    unsigned short* wih0_bf = (unsigned short*)alloc((size_t)3072 * 256 * 2);
    unsigned short* whh0_bf = (unsigned short*)alloc((size_t)3072 * 1024 * 2);
    unsigned short* wih1_bf = (unsigned short*)alloc((size_t)3072 * 1024 * 2);
    unsigned short* whh1_bf = (unsigned short*)alloc((size_t)3072 * 1024 * 2);

    cast_f32_bf16<<<256, 256, 0, stream>>>(input, in_bf, 16384 * 256);
    cast_f32_bf16<<<64, 256, 0, stream>>>(w_ih0, wih0_bf, 3072 * 256);
    cast_f32_bf16<<<256, 256, 0, stream>>>(w_hh0, whh0_bf, 3072 * 1024);
    cast_f32_bf16<<<256, 256, 0, stream>>>(w_ih1, wih1_bf, 3072 * 1024);
    cast_f32_bf16<<<256, 256, 0, stream>>>(w_hh1, whh1_bf, 3072 * 1024);

    hipMemsetAsync(flags, 0, 4096, stream);
    hipMemsetAsync(ring0, 0, (size_t)SLOT * 2, stream);  // h0(0) = 0
    hipMemsetAsync(ring1, 0, (size_t)SLOT * 2, stream);  // h1(0) = 0

    // gx0 = input @ w_ih0^T + b_ih0 (layer-1's gx is computed inside the fused kernel)
    gemm_gx<256><<<12288, 256, 0, stream>>>(in_bf, wih0_bf, b_ih0, gx0);

    gru_fused<<<128, 256, 0, stream>>>(gx0, whh0_bf, b_hh0, wih1_bf, whh1_bf, b_ih1,
                                       b_hh1, ring0, ring1, out + 8192,
                                       out + 8192 + 32768, flags);

    // ---- FC + sigmoid on h_last of layer 1 (ring1 slot TT) ----
    fc_out<<<32, 256, 0, stream>>>(ring1 + (size_t)TT * SLOT, fc_w, fc_b, out);
}

// Round 8
// 5034.527 us; speedup vs baseline: 4.5331x; 1.4130x over previous
//
#include <hip/hip_runtime.h>

#define BB 32
#define TT 512
#define INW 256
#define HH 1024
#define OUTW 256
#define SLOT 32768  // ushorts per ring slot; layout [64 chunks][32 b][16 j]
// 3H = 3072

typedef __attribute__((ext_vector_type(8))) short short8;
typedef __attribute__((ext_vector_type(4))) float floatx4;

__device__ __forceinline__ unsigned short f2bf(float f) {
    unsigned int u = __float_as_uint(f);
    u = (u + 0x7fffu + ((u >> 16) & 1u)) >> 16;
    return (unsigned short)u;
}
__device__ __forceinline__ float bf2f(unsigned short h) {
    return __uint_as_float(((unsigned int)h) << 16);
}

__global__ void cast_f32_bf16(const float* __restrict__ src,
                              unsigned short* __restrict__ dst, int n) {
    int i = blockIdx.x * blockDim.x + threadIdx.x;
    int stride = gridDim.x * blockDim.x;
    for (; i < n; i += stride) dst[i] = f2bf(src[i]);
}

// C_bf16[M x 3072] = X_bf16[M x K] @ W_bf16[3072 x K]^T + bias_f32
template <int K>
__global__ __launch_bounds__(256) void gemm_gx(const unsigned short* __restrict__ X,
                                               const unsigned short* __restrict__ W,
                                               const float* __restrict__ bias,
                                               unsigned short* __restrict__ Cout) {
    __shared__ __align__(16) unsigned short As[64 * 40];
    __shared__ __align__(16) unsigned short Bs[64 * 40];
    int bid = blockIdx.x;
    int tn = bid % 48, tm = bid / 48;
    int tid = threadIdx.x;
    int lane = tid & 63, wv = tid >> 6;
    int wm = wv >> 1, wn = wv & 1;
    int l15 = lane & 15, q = lane >> 4;
    floatx4 acc[2][2] = {};
    int r = tid >> 2, kq = (tid & 3) * 8;
    const unsigned short* xrow = X + (size_t)(tm * 64 + r) * K;
    const unsigned short* wrow = W + (size_t)(tn * 64 + r) * K;
    const int NK = K / 32;
    for (int kk = 0; kk < NK; ++kk) {
        int k0 = kk * 32;
        *(short8*)&As[r * 40 + kq] = *(const short8*)&xrow[k0 + kq];
        *(short8*)&Bs[r * 40 + kq] = *(const short8*)&wrow[k0 + kq];
        __syncthreads();
        short8 a0 = *(const short8*)&As[(wm * 32 + l15) * 40 + q * 8];
        short8 a1 = *(const short8*)&As[(wm * 32 + 16 + l15) * 40 + q * 8];
        short8 b0 = *(const short8*)&Bs[(wn * 32 + l15) * 40 + q * 8];
        short8 b1 = *(const short8*)&Bs[(wn * 32 + 16 + l15) * 40 + q * 8];
        acc[0][0] = __builtin_amdgcn_mfma_f32_16x16x32_bf16(a0, b0, acc[0][0], 0, 0, 0);
        acc[0][1] = __builtin_amdgcn_mfma_f32_16x16x32_bf16(a0, b1, acc[0][1], 0, 0, 0);
        acc[1][0] = __builtin_amdgcn_mfma_f32_16x16x32_bf16(a1, b0, acc[1][0], 0, 0, 0);
        acc[1][1] = __builtin_amdgcn_mfma_f32_16x16x32_bf16(a1, b1, acc[1][1], 0, 0, 0);
        __syncthreads();
    }
    for (int mi = 0; mi < 2; ++mi)
        for (int ni = 0; ni < 2; ++ni) {
            int col = tn * 64 + wn * 32 + ni * 16 + l15;
            float bv = bias[col];
            int row0 = tm * 64 + wm * 32 + mi * 16 + q * 4;
            for (int rr = 0; rr < 4; ++rr) {
                Cout[(size_t)(row0 + rr) * 3072 + col] = f2bf(acc[mi][ni][rr] + bv);
            }
        }
}

// Fused 2-layer persistent GRU, 128 blocks x 256 threads.
// Ring slots use CHUNKED layout [64 chunks][32 b][16 j]: element (b,j) at
// (j>>4)*512 + b*16 + (j&15). Exports: LDS-staged chunk -> 256 contiguous
// dword agent stores (8 full lines). Consumer A-fragment loads are contiguous
// 16B/lane (8 lines/instr). Blocks 0-63 = layer 0; 64-127 = layer 1 one step
// behind, computing w_ih1 and w_hh1 matmuls on the fly. Flag protocol and
// write-once-ring + plain cached loads are the R6/R7-proven primitives.
__global__ __launch_bounds__(256) void gru_fused(
    const unsigned short* __restrict__ gx0, const unsigned short* __restrict__ whh0,
    const float* __restrict__ bhh0, const unsigned short* __restrict__ wih1,
    const unsigned short* __restrict__ whh1, const float* __restrict__ bih1,
    const float* __restrict__ bhh1, unsigned short* __restrict__ ring0,
    unsigned short* __restrict__ ring1, float* __restrict__ hn0,
    float* __restrict__ hn1, unsigned int* __restrict__ flags) {
    __shared__ __align__(16) float red[4 * 8 * 64 * 4];
    __shared__ unsigned int slice32[256];
    const int bid = blockIdx.x;
    const int tid = threadIdx.x;
    const int lane = tid & 63, wv = tid >> 6;
    const int l15 = lane & 15, q = lane >> 4;
    const int kbase = wv * 256;
    const int b = tid & 31, jh = tid >> 5;
    const int mi = b >> 4, reg = b & 3;
    const int rbase = ((b & 15) >> 2) * 16 + 2 * jh;  // MFMA C-layout lane

    if (bid < 64) {
        // ================= layer 0 =================
        const int j0 = bid * 16;
        const unsigned short* wr0 = whh0 + (size_t)(j0 + l15) * HH;
        const unsigned short* wr1 = whh0 + (size_t)(1024 + j0 + l15) * HH;
        const unsigned short* wr2 = whh0 + (size_t)(2048 + j0 + l15) * HH;
        float hpriv[2] = {0.f, 0.f};
        const float bhr0 = bhh0[j0 + 2 * jh], bhr1 = bhh0[j0 + 2 * jh + 1];
        const float bhz0 = bhh0[1024 + j0 + 2 * jh], bhz1 = bhh0[1024 + j0 + 2 * jh + 1];
        const float bhn0 = bhh0[2048 + j0 + 2 * jh], bhn1 = bhh0[2048 + j0 + 2 * jh + 1];
        const unsigned short* gxb = gx0 + (size_t)b * TT * 3072 + j0 + 2 * jh;
        unsigned int pxr = *(const unsigned int*)(gxb);
        unsigned int pxz = *(const unsigned int*)(gxb + 1024);
        unsigned int pxn = *(const unsigned int*)(gxb + 2048);

        for (int t = 0; t < TT; ++t) {
            if (t > 0) {
                unsigned int target = (unsigned int)t;
                while (true) {
                    unsigned int v = __hip_atomic_load(flags + lane, __ATOMIC_RELAXED,
                                                       __HIP_MEMORY_SCOPE_AGENT);
                    if (__all((int)(v >= target))) break;
                    __builtin_amdgcn_s_sleep(1);
                }
                asm volatile("" ::: "memory");
            }
            const unsigned short* hc = ring0 + (size_t)t * SLOT;
            unsigned int cxr = pxr, cxz = pxz, cxn = pxn;

            floatx4 acc[6] = {};
#pragma unroll
            for (int s = 0; s < 8; ++s) {
                int k = kbase + s * 32 + q * 8;
                int cb = (k >> 4) << 9, ko = k & 15;
                short8 a0 = *(const short8*)&hc[cb + (l15 << 4) + ko];
                short8 a1 = *(const short8*)&hc[cb + ((16 + l15) << 4) + ko];
                short8 b0 = *(const short8*)&wr0[k];
                short8 b1 = *(const short8*)&wr1[k];
                short8 b2 = *(const short8*)&wr2[k];
                acc[0] = __builtin_amdgcn_mfma_f32_16x16x32_bf16(a0, b0, acc[0], 0, 0, 0);
                acc[1] = __builtin_amdgcn_mfma_f32_16x16x32_bf16(a0, b1, acc[1], 0, 0, 0);
                acc[2] = __builtin_amdgcn_mfma_f32_16x16x32_bf16(a0, b2, acc[2], 0, 0, 0);
                acc[3] = __builtin_amdgcn_mfma_f32_16x16x32_bf16(a1, b0, acc[3], 0, 0, 0);
                acc[4] = __builtin_amdgcn_mfma_f32_16x16x32_bf16(a1, b1, acc[4], 0, 0, 0);
                acc[5] = __builtin_amdgcn_mfma_f32_16x16x32_bf16(a1, b2, acc[5], 0, 0, 0);
            }
#pragma unroll
            for (int tl = 0; tl < 6; ++tl)
                *(floatx4*)&red[((wv * 6 + tl) * 64 + lane) * 4] = acc[tl];
            __syncthreads();

            float hnew[2];
#pragma unroll
            for (int i = 0; i < 2; ++i) {
                int rl = rbase + i;
                float gr = 0.f, gz = 0.f, gn = 0.f;
#pragma unroll
                for (int w = 0; w < 4; ++w) {
                    gr += red[((w * 6 + mi * 3 + 0) * 64 + rl) * 4 + reg];
                    gz += red[((w * 6 + mi * 3 + 1) * 64 + rl) * 4 + reg];
                    gn += red[((w * 6 + mi * 3 + 2) * 64 + rl) * 4 + reg];
                }
                gr += i ? bhr1 : bhr0;
                gz += i ? bhz1 : bhz0;
                gn += i ? bhn1 : bhn0;
                float xr = bf2f((unsigned short)(i ? (cxr >> 16) : (cxr & 0xffffu)));
                float xz = bf2f((unsigned short)(i ? (cxz >> 16) : (cxz & 0xffffu)));
                float xn = bf2f((unsigned short)(i ? (cxn >> 16) : (cxn & 0xffffu)));
                float rg = 1.f / (1.f + __expf(-(xr + gr)));
                float zg = 1.f / (1.f + __expf(-(xz + gz)));
                float ng = tanhf(xn + rg * gn);
                hnew[i] = (1.f - zg) * ng + zg * hpriv[i];
                hpriv[i] = hnew[i];
            }
            unsigned int hpack =
                (unsigned int)f2bf(hnew[0]) | ((unsigned int)f2bf(hnew[1]) << 16);
            slice32[b * 8 + jh] = hpack;
            __syncthreads();
            // export own chunk: 256 contiguous dwords = 8 full lines
            {
                unsigned int* dst =
                    (unsigned int*)(ring0 + (size_t)(t + 1) * SLOT) + (bid << 8) + tid;
                __hip_atomic_store(dst, slice32[tid], __ATOMIC_RELAXED,
                                   __HIP_MEMORY_SCOPE_AGENT);
            }
            asm volatile("s_waitcnt vmcnt(0)" ::: "memory");
            __syncthreads();
            if (tid == 0)
                __hip_atomic_store(flags + bid, (unsigned int)(t + 1), __ATOMIC_RELAXED,
                                   __HIP_MEMORY_SCOPE_AGENT);
            if (t == TT - 1) {
                int jj = b * HH + j0 + 2 * jh;
                hn0[jj] = hnew[0];
                hn0[jj + 1] = hnew[1];
            }
            if (t + 1 < TT) {
                const unsigned short* g2 = gxb + (size_t)(t + 1) * 3072;
                pxr = *(const unsigned int*)(g2);
                pxz = *(const unsigned int*)(g2 + 1024);
                pxn = *(const unsigned int*)(g2 + 2048);
            }
        }
    } else {
        // ================= layer 1 (one step behind) =================
        const int b2 = bid - 64;
        const int j0 = b2 * 16;
        const unsigned short* wi0 = wih1 + (size_t)(j0 + l15) * HH;
        const unsigned short* wi1 = wih1 + (size_t)(1024 + j0 + l15) * HH;
        const unsigned short* wi2 = wih1 + (size_t)(2048 + j0 + l15) * HH;
        const unsigned short* wh0 = whh1 + (size_t)(j0 + l15) * HH;
        const unsigned short* wh1 = whh1 + (size_t)(1024 + j0 + l15) * HH;
        const unsigned short* wh2 = whh1 + (size_t)(2048 + j0 + l15) * HH;
        float hpriv[2] = {0.f, 0.f};
        const float cR0 = bih1[j0 + 2 * jh] + bhh1[j0 + 2 * jh];
        const float cR1 = bih1[j0 + 2 * jh + 1] + bhh1[j0 + 2 * jh + 1];
        const float cZ0 = bih1[1024 + j0 + 2 * jh] + bhh1[1024 + j0 + 2 * jh];
        const float cZ1 = bih1[1024 + j0 + 2 * jh + 1] + bhh1[1024 + j0 + 2 * jh + 1];
        const float cNx0 = bih1[2048 + j0 + 2 * jh];
        const float cNx1 = bih1[2048 + j0 + 2 * jh + 1];
        const float cNh0 = bhh1[2048 + j0 + 2 * jh];
        const float cNh1 = bhh1[2048 + j0 + 2 * jh + 1];

        for (int t = 0; t < TT; ++t) {
            floatx4 acc[8] = {};  // mi*4 + {r, z, nx, nh}
            // ---- phase A: x-part (h0(t) = ring0 slot t+1; L0 runs ahead)
            {
                unsigned int tgt0 = (unsigned int)(t + 1);
                while (true) {
                    unsigned int v0 = __hip_atomic_load(flags + lane, __ATOMIC_RELAXED,
                                                        __HIP_MEMORY_SCOPE_AGENT);
                    if (__all((int)(v0 >= tgt0))) break;
                    __builtin_amdgcn_s_sleep(1);
                }
                asm volatile("" ::: "memory");
            }
            const unsigned short* x0 = ring0 + (size_t)(t + 1) * SLOT;
#pragma unroll
            for (int s = 0; s < 8; ++s) {
                int k = kbase + s * 32 + q * 8;
                int cb = (k >> 4) << 9, ko = k & 15;
                short8 xa0 = *(const short8*)&x0[cb + (l15 << 4) + ko];
                short8 xa1 = *(const short8*)&x0[cb + ((16 + l15) << 4) + ko];
                short8 fir = *(const short8*)&wi0[k];
                short8 fiz = *(const short8*)&wi1[k];
                short8 fin = *(const short8*)&wi2[k];
                acc[0] = __builtin_amdgcn_mfma_f32_16x16x32_bf16(xa0, fir, acc[0], 0, 0, 0);
                acc[1] = __builtin_amdgcn_mfma_f32_16x16x32_bf16(xa0, fiz, acc[1], 0, 0, 0);
                acc[2] = __builtin_amdgcn_mfma_f32_16x16x32_bf16(xa0, fin, acc[2], 0, 0, 0);
                acc[4] = __builtin_amdgcn_mfma_f32_16x16x32_bf16(xa1, fir, acc[4], 0, 0, 0);
                acc[5] = __builtin_amdgcn_mfma_f32_16x16x32_bf16(xa1, fiz, acc[5], 0, 0, 0);
                acc[6] = __builtin_amdgcn_mfma_f32_16x16x32_bf16(xa1, fin, acc[6], 0, 0, 0);
            }
            // ---- phase B: h-part (own-layer dependency)
            if (t > 0) {
                unsigned int tgt1 = (unsigned int)t;
                while (true) {
                    unsigned int v1 = __hip_atomic_load(flags + 64 + lane,
                                                        __ATOMIC_RELAXED,
                                                        __HIP_MEMORY_SCOPE_AGENT);
                    if (__all((int)(v1 >= tgt1))) break;
                    __builtin_amdgcn_s_sleep(1);
                }
                asm volatile("" ::: "memory");
            }
            const unsigned short* h1c = ring1 + (size_t)t * SLOT;
#pragma unroll
            for (int s = 0; s < 8; ++s) {
                int k = kbase + s * 32 + q * 8;
                int cb = (k >> 4) << 9, ko = k & 15;
                short8 ha0 = *(const short8*)&h1c[cb + (l15 << 4) + ko];
                short8 ha1 = *(const short8*)&h1c[cb + ((16 + l15) << 4) + ko];
                short8 fhr = *(const short8*)&wh0[k];
                short8 fhz = *(const short8*)&wh1[k];
                short8 fhn = *(const short8*)&wh2[k];
                acc[0] = __builtin_amdgcn_mfma_f32_16x16x32_bf16(ha0, fhr, acc[0], 0, 0, 0);
                acc[1] = __builtin_amdgcn_mfma_f32_16x16x32_bf16(ha0, fhz, acc[1], 0, 0, 0);
                acc[3] = __builtin_amdgcn_mfma_f32_16x16x32_bf16(ha0, fhn, acc[3], 0, 0, 0);
                acc[4] = __builtin_amdgcn_mfma_f32_16x16x32_bf16(ha1, fhr, acc[4], 0, 0, 0);
                acc[5] = __builtin_amdgcn_mfma_f32_16x16x32_bf16(ha1, fhz, acc[5], 0, 0, 0);
                acc[7] = __builtin_amdgcn_mfma_f32_16x16x32_bf16(ha1, fhn, acc[7], 0, 0, 0);
            }
#pragma unroll
            for (int tl = 0; tl < 8; ++tl)
                *(floatx4*)&red[((wv * 8 + tl) * 64 + lane) * 4] = acc[tl];
            __syncthreads();

            float hnew[2];
#pragma unroll
            for (int i = 0; i < 2; ++i) {
                int rl = rbase + i;
                float gr = 0.f, gz = 0.f, xn = 0.f, hnp = 0.f;
#pragma unroll
                for (int w = 0; w < 4; ++w) {
                    gr += red[((w * 8 + mi * 4 + 0) * 64 + rl) * 4 + reg];
                    gz += red[((w * 8 + mi * 4 + 1) * 64 + rl) * 4 + reg];
                    xn += red[((w * 8 + mi * 4 + 2) * 64 + rl) * 4 + reg];
                    hnp += red[((w * 8 + mi * 4 + 3) * 64 + rl) * 4 + reg];
                }
                gr += i ? cR1 : cR0;
                gz += i ? cZ1 : cZ0;
                xn += i ? cNx1 : cNx0;
                hnp += i ? cNh1 : cNh0;
                float rg = 1.f / (1.f + __expf(-gr));
                float zg = 1.f / (1.f + __expf(-gz));
                float ng = tanhf(xn + rg * hnp);
                hnew[i] = (1.f - zg) * ng + zg * hpriv[i];
                hpriv[i] = hnew[i];
            }
            unsigned int hpack =
                (unsigned int)f2bf(hnew[0]) | ((unsigned int)f2bf(hnew[1]) << 16);
            slice32[b * 8 + jh] = hpack;
            __syncthreads();
            {
                unsigned int* dst =
                    (unsigned int*)(ring1 + (size_t)(t + 1) * SLOT) + (b2 << 8) + tid;
                __hip_atomic_store(dst, slice32[tid], __ATOMIC_RELAXED,
                                   __HIP_MEMORY_SCOPE_AGENT);
            }
            asm volatile("s_waitcnt vmcnt(0)" ::: "memory");
            __syncthreads();
            if (tid == 0)
                __hip_atomic_store(flags + 64 + b2, (unsigned int)(t + 1),
                                   __ATOMIC_RELAXED, __HIP_MEMORY_SCOPE_AGENT);
            if (t == TT - 1) {
                int jj = b * HH + j0 + 2 * jh;
                hn1[jj] = hnew[0];
                hn1[jj + 1] = hnew[1];
            }
        }
    }
}

// h1bf is ring1 slot TT in chunked layout: (b,k) at (k>>4)*512 + b*16 + (k&15)
__global__ void fc_out(const unsigned short* __restrict__ h1bf,
                       const float* __restrict__ fcw, const float* __restrict__ fcb,
                       float* __restrict__ out) {
    int b = blockIdx.x, o = threadIdx.x;  // 32 x 256
    const float* wr = fcw + (size_t)o * HH;
    float acc = fcb[o];
    for (int k = 0; k < HH; k += 16) {
        const unsigned short* hp = h1bf + ((k >> 4) << 9) + (b << 4);
#pragma unroll
        for (int i = 0; i < 16; ++i) acc += bf2f(hp[i]) * wr[k + i];
    }
    out[b * OUTW + o] = 1.f / (1.f + expf(-acc));
}

extern "C" void kernel_launch(void* const* d_in, const int* in_sizes, int n_in,
                              void* d_out, int out_size, void* d_ws, size_t ws_size,
                              hipStream_t stream) {
    (void)in_sizes; (void)n_in; (void)out_size; (void)ws_size;
    const float* input = (const float*)d_in[0];
    const float* w_ih0 = (const float*)d_in[1];
    const float* w_hh0 = (const float*)d_in[2];
    const float* b_ih0 = (const float*)d_in[3];
    const float* b_hh0 = (const float*)d_in[4];
    const float* w_ih1 = (const float*)d_in[5];
    const float* w_hh1 = (const float*)d_in[6];
    const float* b_ih1 = (const float*)d_in[7];
    const float* b_hh1 = (const float*)d_in[8];
    const float* fc_w = (const float*)d_in[9];
    const float* fc_b = (const float*)d_in[10];
    float* out = (float*)d_out;

    char* ws = (char*)d_ws;
    size_t off = 0;
    auto alloc = [&](size_t bytes) {
        void* p = ws + off;
        off += (bytes + 255) & ~(size_t)255;
        return p;
    };
    unsigned int* flags = (unsigned int*)alloc(4096);  // L0: [0..64), L1: [64..128)
    unsigned short* ring0 = (unsigned short*)alloc((size_t)(TT + 1) * SLOT * 2);
    unsigned short* ring1 = (unsigned short*)alloc((size_t)(TT + 1) * SLOT * 2);
    unsigned short* gx0 = (unsigned short*)alloc((size_t)16384 * 3072 * 2);
    unsigned short* in_bf = (unsigned short*)alloc((size_t)16384 * 256 * 2);
    unsigned short* wih0_bf = (unsigned short*)alloc((size_t)3072 * 256 * 2);
    unsigned short* whh0_bf = (unsigned short*)alloc((size_t)3072 * 1024 * 2);
    unsigned short* wih1_bf = (unsigned short*)alloc((size_t)3072 * 1024 * 2);
    unsigned short* whh1_bf = (unsigned short*)alloc((size_t)3072 * 1024 * 2);

    cast_f32_bf16<<<256, 256, 0, stream>>>(input, in_bf, 16384 * 256);
    cast_f32_bf16<<<64, 256, 0, stream>>>(w_ih0, wih0_bf, 3072 * 256);
    cast_f32_bf16<<<256, 256, 0, stream>>>(w_hh0, whh0_bf, 3072 * 1024);
    cast_f32_bf16<<<256, 256, 0, stream>>>(w_ih1, wih1_bf, 3072 * 1024);
    cast_f32_bf16<<<256, 256, 0, stream>>>(w_hh1, whh1_bf, 3072 * 1024);

    hipMemsetAsync(flags, 0, 4096, stream);
    hipMemsetAsync(ring0, 0, (size_t)SLOT * 2, stream);  // h0(0) = 0
    hipMemsetAsync(ring1, 0, (size_t)SLOT * 2, stream);  // h1(0) = 0

    // gx0 = input @ w_ih0^T + b_ih0 (layer-1 projections fused into gru kernel)
    gemm_gx<256><<<12288, 256, 0, stream>>>(in_bf, wih0_bf, b_ih0, gx0);

    gru_fused<<<128, 256, 0, stream>>>(gx0, whh0_bf, b_hh0, wih1_bf, whh1_bf, b_ih1,
                                       b_hh1, ring0, ring1, out + 8192,
                                       out + 8192 + 32768, flags);

    // ---- FC + sigmoid on h_last of layer 1 (ring1 slot TT, chunked) ----
    fc_out<<<32, 256, 0, stream>>>(ring1 + (size_t)TT * SLOT, fc_w, fc_b, out);
}

// Round 9
// 3800.890 us; speedup vs baseline: 6.0044x; 1.3246x over previous
//
#include <hip/hip_runtime.h>

#define BB 32
#define TT 512
#define INW 256
#define HH 1024
#define OUTW 256
#define SLOT 32768  // ushorts per ring slot; layout [64 chunks][32 b][16 j]
// 3H = 3072

typedef __attribute__((ext_vector_type(8))) short short8;
typedef __attribute__((ext_vector_type(4))) float floatx4;

__device__ __forceinline__ unsigned short f2bf(float f) {
    unsigned int u = __float_as_uint(f);
    u = (u + 0x7fffu + ((u >> 16) & 1u)) >> 16;
    return (unsigned short)u;
}
__device__ __forceinline__ float bf2f(unsigned short h) {
    return __uint_as_float(((unsigned int)h) << 16);
}

__global__ void cast_f32_bf16(const float* __restrict__ src,
                              unsigned short* __restrict__ dst, int n) {
    int i = blockIdx.x * blockDim.x + threadIdx.x;
    int stride = gridDim.x * blockDim.x;
    for (; i < n; i += stride) dst[i] = f2bf(src[i]);
}

// C_bf16[M x 3072] = X_bf16[M x K] @ W_bf16[3072 x K]^T + bias_f32
template <int K>
__global__ __launch_bounds__(256) void gemm_gx(const unsigned short* __restrict__ X,
                                               const unsigned short* __restrict__ W,
                                               const float* __restrict__ bias,
                                               unsigned short* __restrict__ Cout) {
    __shared__ __align__(16) unsigned short As[64 * 40];
    __shared__ __align__(16) unsigned short Bs[64 * 40];
    int bid = blockIdx.x;
    int tn = bid % 48, tm = bid / 48;
    int tid = threadIdx.x;
    int lane = tid & 63, wv = tid >> 6;
    int wm = wv >> 1, wn = wv & 1;
    int l15 = lane & 15, q = lane >> 4;
    floatx4 acc[2][2] = {};
    int r = tid >> 2, kq = (tid & 3) * 8;
    const unsigned short* xrow = X + (size_t)(tm * 64 + r) * K;
    const unsigned short* wrow = W + (size_t)(tn * 64 + r) * K;
    const int NK = K / 32;
    for (int kk = 0; kk < NK; ++kk) {
        int k0 = kk * 32;
        *(short8*)&As[r * 40 + kq] = *(const short8*)&xrow[k0 + kq];
        *(short8*)&Bs[r * 40 + kq] = *(const short8*)&wrow[k0 + kq];
        __syncthreads();
        short8 a0 = *(const short8*)&As[(wm * 32 + l15) * 40 + q * 8];
        short8 a1 = *(const short8*)&As[(wm * 32 + 16 + l15) * 40 + q * 8];
        short8 b0 = *(const short8*)&Bs[(wn * 32 + l15) * 40 + q * 8];
        short8 b1 = *(const short8*)&Bs[(wn * 32 + 16 + l15) * 40 + q * 8];
        acc[0][0] = __builtin_amdgcn_mfma_f32_16x16x32_bf16(a0, b0, acc[0][0], 0, 0, 0);
        acc[0][1] = __builtin_amdgcn_mfma_f32_16x16x32_bf16(a0, b1, acc[0][1], 0, 0, 0);
        acc[1][0] = __builtin_amdgcn_mfma_f32_16x16x32_bf16(a1, b0, acc[1][0], 0, 0, 0);
        acc[1][1] = __builtin_amdgcn_mfma_f32_16x16x32_bf16(a1, b1, acc[1][1], 0, 0, 0);
        __syncthreads();
    }
    for (int mi = 0; mi < 2; ++mi)
        for (int ni = 0; ni < 2; ++ni) {
            int col = tn * 64 + wn * 32 + ni * 16 + l15;
            float bv = bias[col];
            int row0 = tm * 64 + wm * 32 + mi * 16 + q * 4;
            for (int rr = 0; rr < 4; ++rr) {
                Cout[(size_t)(row0 + rr) * 3072 + col] = f2bf(acc[mi][ni][rr] + bv);
            }
        }
}

// Fused 2-layer persistent GRU, 128 blocks x 512 threads (8 waves).
// Blocks 0-63 (L0): 8-way K-split (K=128/wave) of the whh0 matmul.
// Blocks 64-127 (L1): WAVE-SPECIALIZED — waves 0-3 h-part (ring1 critical
// path), waves 4-7 x-part (ring0; L0 runs ahead so it never blocks). Both dump
// 6 tiles each into the reduce buffer; gate sums h/x parts (n kept split).
// Single-wave polling: only wave 0 (+ wave 4 in L1) polls the agent-scope
// flags; others wait at the entry __syncthreads — cuts coherence-point
// read pressure on the flag lines ~3x.
// Ring slots chunked [64][32 b][16 j]; write-once -> plain cached consumer
// loads; producer export = 256 contiguous dwords + vmcnt(0) + flag (R6-R8).
__global__ __launch_bounds__(512) void gru_fused(
    const unsigned short* __restrict__ gx0, const unsigned short* __restrict__ whh0,
    const float* __restrict__ bhh0, const unsigned short* __restrict__ wih1,
    const unsigned short* __restrict__ whh1, const float* __restrict__ bih1,
    const float* __restrict__ bhh1, unsigned short* __restrict__ ring0,
    unsigned short* __restrict__ ring1, float* __restrict__ hn0,
    float* __restrict__ hn1, unsigned int* __restrict__ flags) {
    __shared__ __align__(16) float red[8 * 6 * 64 * 4];  // 48 KB
    __shared__ __align__(16) unsigned short slice16[512];
    const int bid = blockIdx.x;
    const int tid = threadIdx.x;
    const int lane = tid & 63, wv = tid >> 6;
    const int l15 = lane & 15, q = lane >> 4;
    // gate-phase ownership: one thread per (b, jl) element
    const int b = tid & 31, jl = tid >> 5;           // jl in [0,16)
    const int mi = b >> 4, reg = b & 3;
    const int rl = ((b & 15) >> 2) * 16 + jl;        // MFMA C-layout lane

    if (bid < 64) {
        // ================= layer 0 : 8-way K-split =================
        const int j0 = bid * 16;
        const int kbase = wv * 128;
        const unsigned short* wr0 = whh0 + (size_t)(j0 + l15) * HH;
        const unsigned short* wr1 = whh0 + (size_t)(1024 + j0 + l15) * HH;
        const unsigned short* wr2 = whh0 + (size_t)(2048 + j0 + l15) * HH;
        const float bR = bhh0[j0 + jl], bZ = bhh0[1024 + j0 + jl],
                    bN = bhh0[2048 + j0 + jl];
        float hpriv = 0.f;
        const unsigned short* gxp = gx0 + (size_t)b * TT * 3072 + j0 + jl;
        unsigned short pxr = gxp[0], pxz = gxp[1024], pxn = gxp[2048];

        for (int t = 0; t < TT; ++t) {
            if (t > 0 && wv == 0) {  // single-wave poll of own-layer flags
                unsigned int target = (unsigned int)t;
                while (true) {
                    unsigned int v = __hip_atomic_load(flags + lane, __ATOMIC_RELAXED,
                                                       __HIP_MEMORY_SCOPE_AGENT);
                    if (__all((int)(v >= target))) break;
                    __builtin_amdgcn_s_sleep(1);
                }
            }
            __syncthreads();
            const unsigned short* hc = ring0 + (size_t)t * SLOT;
            unsigned short cxr = pxr, cxz = pxz, cxn = pxn;

            floatx4 acc[6] = {};
#pragma unroll
            for (int s = 0; s < 4; ++s) {
                int k = kbase + s * 32 + q * 8;
                int cb = (k >> 4) << 9, ko = k & 15;
                short8 a0 = *(const short8*)&hc[cb + (l15 << 4) + ko];
                short8 a1 = *(const short8*)&hc[cb + ((16 + l15) << 4) + ko];
                short8 b0 = *(const short8*)&wr0[k];
                short8 b1 = *(const short8*)&wr1[k];
                short8 b2 = *(const short8*)&wr2[k];
                acc[0] = __builtin_amdgcn_mfma_f32_16x16x32_bf16(a0, b0, acc[0], 0, 0, 0);
                acc[1] = __builtin_amdgcn_mfma_f32_16x16x32_bf16(a0, b1, acc[1], 0, 0, 0);
                acc[2] = __builtin_amdgcn_mfma_f32_16x16x32_bf16(a0, b2, acc[2], 0, 0, 0);
                acc[3] = __builtin_amdgcn_mfma_f32_16x16x32_bf16(a1, b0, acc[3], 0, 0, 0);
                acc[4] = __builtin_amdgcn_mfma_f32_16x16x32_bf16(a1, b1, acc[4], 0, 0, 0);
                acc[5] = __builtin_amdgcn_mfma_f32_16x16x32_bf16(a1, b2, acc[5], 0, 0, 0);
            }
#pragma unroll
            for (int tl = 0; tl < 6; ++tl)
                *(floatx4*)&red[((wv * 6 + tl) * 64 + lane) * 4] = acc[tl];
            __syncthreads();

            float gr = 0.f, gz = 0.f, gn = 0.f;
#pragma unroll
            for (int w = 0; w < 8; ++w) {
                gr += red[((w * 6 + mi * 3 + 0) * 64 + rl) * 4 + reg];
                gz += red[((w * 6 + mi * 3 + 1) * 64 + rl) * 4 + reg];
                gn += red[((w * 6 + mi * 3 + 2) * 64 + rl) * 4 + reg];
            }
            float rg = 1.f / (1.f + __expf(-(bf2f(cxr) + gr + bR)));
            float zg = 1.f / (1.f + __expf(-(bf2f(cxz) + gz + bZ)));
            float ng = tanhf(bf2f(cxn) + rg * (gn + bN));
            float hnew = (1.f - zg) * ng + zg * hpriv;
            hpriv = hnew;
            slice16[b * 16 + jl] = f2bf(hnew);
            __syncthreads();
            if (tid < 256) {  // export own chunk: 256 contiguous dwords
                unsigned int* dst =
                    (unsigned int*)(ring0 + (size_t)(t + 1) * SLOT) + (bid << 8) + tid;
                __hip_atomic_store(dst, ((unsigned int*)slice16)[tid], __ATOMIC_RELAXED,
                                   __HIP_MEMORY_SCOPE_AGENT);
                asm volatile("s_waitcnt vmcnt(0)" ::: "memory");
            }
            __syncthreads();
            if (tid == 0)
                __hip_atomic_store(flags + bid, (unsigned int)(t + 1), __ATOMIC_RELAXED,
                                   __HIP_MEMORY_SCOPE_AGENT);
            if (t == TT - 1) hn0[b * HH + j0 + jl] = hnew;
            if (t + 1 < TT) {
                const unsigned short* g2 = gxp + (size_t)(t + 1) * 3072;
                pxr = g2[0];
                pxz = g2[1024];
                pxn = g2[2048];
            }
        }
    } else {
        // ========== layer 1 : wave-specialized (h-waves 0-3, x-waves 4-7) ==========
        const int b2 = bid - 64;
        const int j0 = b2 * 16;
        const bool isx = (wv >= 4);
        const int kbase = (wv & 3) * 256;
        // h-waves use whh1 rows; x-waves use wih1 rows
        const unsigned short* w0 = (isx ? wih1 : whh1) + (size_t)(j0 + l15) * HH;
        const unsigned short* w1 = (isx ? wih1 : whh1) + (size_t)(1024 + j0 + l15) * HH;
        const unsigned short* w2 = (isx ? wih1 : whh1) + (size_t)(2048 + j0 + l15) * HH;
        const float cR = bih1[j0 + jl] + bhh1[j0 + jl];
        const float cZ = bih1[1024 + j0 + jl] + bhh1[1024 + j0 + jl];
        const float cNx = bih1[2048 + j0 + jl];
        const float cNh = bhh1[2048 + j0 + jl];
        float hpriv = 0.f;

        for (int t = 0; t < TT; ++t) {
            if (t > 0 && wv == 0) {  // poll own-layer flags (ring1 critical path)
                unsigned int target = (unsigned int)t;
                while (true) {
                    unsigned int v = __hip_atomic_load(flags + 64 + lane,
                                                       __ATOMIC_RELAXED,
                                                       __HIP_MEMORY_SCOPE_AGENT);
                    if (__all((int)(v >= target))) break;
                    __builtin_amdgcn_s_sleep(1);
                }
            }
            if (wv == 4) {  // poll L0 flags for h0(t) = ring0 slot t+1 (runs ahead)
                unsigned int target = (unsigned int)(t + 1);
                while (true) {
                    unsigned int v = __hip_atomic_load(flags + lane, __ATOMIC_RELAXED,
                                                       __HIP_MEMORY_SCOPE_AGENT);
                    if (__all((int)(v >= target))) break;
                    __builtin_amdgcn_s_sleep(1);
                }
            }
            __syncthreads();
            const unsigned short* src =
                isx ? (ring0 + (size_t)(t + 1) * SLOT) : (ring1 + (size_t)t * SLOT);

            floatx4 acc[6] = {};
#pragma unroll
            for (int s = 0; s < 8; ++s) {
                int k = kbase + s * 32 + q * 8;
                int cb = (k >> 4) << 9, ko = k & 15;
                short8 a0 = *(const short8*)&src[cb + (l15 << 4) + ko];
                short8 a1 = *(const short8*)&src[cb + ((16 + l15) << 4) + ko];
                short8 b0 = *(const short8*)&w0[k];
                short8 b1 = *(const short8*)&w1[k];
                short8 b2 = *(const short8*)&w2[k];
                acc[0] = __builtin_amdgcn_mfma_f32_16x16x32_bf16(a0, b0, acc[0], 0, 0, 0);
                acc[1] = __builtin_amdgcn_mfma_f32_16x16x32_bf16(a0, b1, acc[1], 0, 0, 0);
                acc[2] = __builtin_amdgcn_mfma_f32_16x16x32_bf16(a0, b2, acc[2], 0, 0, 0);
                acc[3] = __builtin_amdgcn_mfma_f32_16x16x32_bf16(a1, b0, acc[3], 0, 0, 0);
                acc[4] = __builtin_amdgcn_mfma_f32_16x16x32_bf16(a1, b1, acc[4], 0, 0, 0);
                acc[5] = __builtin_amdgcn_mfma_f32_16x16x32_bf16(a1, b2, acc[5], 0, 0, 0);
            }
#pragma unroll
            for (int tl = 0; tl < 6; ++tl)
                *(floatx4*)&red[((wv * 6 + tl) * 64 + lane) * 4] = acc[tl];
            __syncthreads();

            // gate: sum r,z over all 8 waves; n split into h (waves 0-3) and
            // x (waves 4-7) parts
            float gr = 0.f, gz = 0.f, hn = 0.f, xn = 0.f;
#pragma unroll
            for (int w = 0; w < 4; ++w) {
                gr += red[((w * 6 + mi * 3 + 0) * 64 + rl) * 4 + reg];
                gz += red[((w * 6 + mi * 3 + 1) * 64 + rl) * 4 + reg];
                hn += red[((w * 6 + mi * 3 + 2) * 64 + rl) * 4 + reg];
            }
#pragma unroll
            for (int w = 4; w < 8; ++w) {
                gr += red[((w * 6 + mi * 3 + 0) * 64 + rl) * 4 + reg];
                gz += red[((w * 6 + mi * 3 + 1) * 64 + rl) * 4 + reg];
                xn += red[((w * 6 + mi * 3 + 2) * 64 + rl) * 4 + reg];
            }
            float rg = 1.f / (1.f + __expf(-(gr + cR)));
            float zg = 1.f / (1.f + __expf(-(gz + cZ)));
            float ng = tanhf(xn + cNx + rg * (hn + cNh));
            float hnew = (1.f - zg) * ng + zg * hpriv;
            hpriv = hnew;
            slice16[b * 16 + jl] = f2bf(hnew);
            __syncthreads();
            if (tid < 256) {
                unsigned int* dst =
                    (unsigned int*)(ring1 + (size_t)(t + 1) * SLOT) + (b2 << 8) + tid;
                __hip_atomic_store(dst, ((unsigned int*)slice16)[tid], __ATOMIC_RELAXED,
                                   __HIP_MEMORY_SCOPE_AGENT);
                asm volatile("s_waitcnt vmcnt(0)" ::: "memory");
            }
            __syncthreads();
            if (tid == 0)
                __hip_atomic_store(flags + 64 + b2, (unsigned int)(t + 1),
                                   __ATOMIC_RELAXED, __HIP_MEMORY_SCOPE_AGENT);
            if (t == TT - 1) hn1[b * HH + j0 + jl] = hnew;
        }
    }
}

// h1bf is ring1 slot TT in chunked layout: (b,k) at (k>>4)*512 + b*16 + (k&15)
__global__ void fc_out(const unsigned short* __restrict__ h1bf,
                       const float* __restrict__ fcw, const float* __restrict__ fcb,
                       float* __restrict__ out) {
    int b = blockIdx.x, o = threadIdx.x;  // 32 x 256
    const float* wr = fcw + (size_t)o * HH;
    float acc = fcb[o];
    for (int k = 0; k < HH; k += 16) {
        const unsigned short* hp = h1bf + ((k >> 4) << 9) + (b << 4);
#pragma unroll
        for (int i = 0; i < 16; ++i) acc += bf2f(hp[i]) * wr[k + i];
    }
    out[b * OUTW + o] = 1.f / (1.f + expf(-acc));
}

extern "C" void kernel_launch(void* const* d_in, const int* in_sizes, int n_in,
                              void* d_out, int out_size, void* d_ws, size_t ws_size,
                              hipStream_t stream) {
    (void)in_sizes; (void)n_in; (void)out_size; (void)ws_size;
    const float* input = (const float*)d_in[0];
    const float* w_ih0 = (const float*)d_in[1];
    const float* w_hh0 = (const float*)d_in[2];
    const float* b_ih0 = (const float*)d_in[3];
    const float* b_hh0 = (const float*)d_in[4];
    const float* w_ih1 = (const float*)d_in[5];
    const float* w_hh1 = (const float*)d_in[6];
    const float* b_ih1 = (const float*)d_in[7];
    const float* b_hh1 = (const float*)d_in[8];
    const float* fc_w = (const float*)d_in[9];
    const float* fc_b = (const float*)d_in[10];
    float* out = (float*)d_out;

    char* ws = (char*)d_ws;
    size_t off = 0;
    auto alloc = [&](size_t bytes) {
        void* p = ws + off;
        off += (bytes + 255) & ~(size_t)255;
        return p;
    };
    unsigned int* flags = (unsigned int*)alloc(4096);  // L0: [0..64), L1: [64..128)
    unsigned short* ring0 = (unsigned short*)alloc((size_t)(TT + 1) * SLOT * 2);
    unsigned short* ring1 = (unsigned short*)alloc((size_t)(TT + 1) * SLOT * 2);
    unsigned short* gx0 = (unsigned short*)alloc((size_t)16384 * 3072 * 2);
    unsigned short* in_bf = (unsigned short*)alloc((size_t)16384 * 256 * 2);
    unsigned short* wih0_bf = (unsigned short*)alloc((size_t)3072 * 256 * 2);
    unsigned short* whh0_bf = (unsigned short*)alloc((size_t)3072 * 1024 * 2);
    unsigned short* wih1_bf = (unsigned short*)alloc((size_t)3072 * 1024 * 2);
    unsigned short* whh1_bf = (unsigned short*)alloc((size_t)3072 * 1024 * 2);

    cast_f32_bf16<<<256, 256, 0, stream>>>(input, in_bf, 16384 * 256);
    cast_f32_bf16<<<64, 256, 0, stream>>>(w_ih0, wih0_bf, 3072 * 256);
    cast_f32_bf16<<<256, 256, 0, stream>>>(w_hh0, whh0_bf, 3072 * 1024);
    cast_f32_bf16<<<256, 256, 0, stream>>>(w_ih1, wih1_bf, 3072 * 1024);
    cast_f32_bf16<<<256, 256, 0, stream>>>(w_hh1, whh1_bf, 3072 * 1024);

    hipMemsetAsync(flags, 0, 4096, stream);
    hipMemsetAsync(ring0, 0, (size_t)SLOT * 2, stream);  // h0(0) = 0
    hipMemsetAsync(ring1, 0, (size_t)SLOT * 2, stream);  // h1(0) = 0

    // gx0 = input @ w_ih0^T + b_ih0 (layer-1 projections fused into gru kernel)
    gemm_gx<256><<<12288, 256, 0, stream>>>(in_bf, wih0_bf, b_ih0, gx0);

    gru_fused<<<128, 512, 0, stream>>>(gx0, whh0_bf, b_hh0, wih1_bf, whh1_bf, b_ih1,
                                       b_hh1, ring0, ring1, out + 8192,
                                       out + 8192 + 32768, flags);

    // ---- FC + sigmoid on h_last of layer 1 (ring1 slot TT, chunked) ----
    fc_out<<<32, 256, 0, stream>>>(ring1 + (size_t)TT * SLOT, fc_w, fc_b, out);
}

// Round 10
// 3526.763 us; speedup vs baseline: 6.4711x; 1.0777x over previous
//
#include <hip/hip_runtime.h>

#define BB 32
#define TT 512
#define INW 256
#define HH 1024
#define OUTW 256
#define SLOT 32768  // ushorts per ring slot; layout [64 chunks][32 b][16 j]
// 3H = 3072

typedef __attribute__((ext_vector_type(8))) short short8;
typedef __attribute__((ext_vector_type(4))) float floatx4;

__device__ __forceinline__ unsigned short f2bf(float f) {
    unsigned int u = __float_as_uint(f);
    u = (u + 0x7fffu + ((u >> 16) & 1u)) >> 16;
    return (unsigned short)u;
}
__device__ __forceinline__ float bf2f(unsigned short h) {
    return __uint_as_float(((unsigned int)h) << 16);
}

__global__ void cast_f32_bf16(const float* __restrict__ src,
                              unsigned short* __restrict__ dst, int n) {
    int i = blockIdx.x * blockDim.x + threadIdx.x;
    int stride = gridDim.x * blockDim.x;
    for (; i < n; i += stride) dst[i] = f2bf(src[i]);
}

// C_bf16[M x 3072] = X_bf16[M x K] @ W_bf16[3072 x K]^T + bias_f32
template <int K>
__global__ __launch_bounds__(256) void gemm_gx(const unsigned short* __restrict__ X,
                                               const unsigned short* __restrict__ W,
                                               const float* __restrict__ bias,
                                               unsigned short* __restrict__ Cout) {
    __shared__ __align__(16) unsigned short As[64 * 40];
    __shared__ __align__(16) unsigned short Bs[64 * 40];
    int bid = blockIdx.x;
    int tn = bid % 48, tm = bid / 48;
    int tid = threadIdx.x;
    int lane = tid & 63, wv = tid >> 6;
    int wm = wv >> 1, wn = wv & 1;
    int l15 = lane & 15, q = lane >> 4;
    floatx4 acc[2][2] = {};
    int r = tid >> 2, kq = (tid & 3) * 8;
    const unsigned short* xrow = X + (size_t)(tm * 64 + r) * K;
    const unsigned short* wrow = W + (size_t)(tn * 64 + r) * K;
    const int NK = K / 32;
    for (int kk = 0; kk < NK; ++kk) {
        int k0 = kk * 32;
        *(short8*)&As[r * 40 + kq] = *(const short8*)&xrow[k0 + kq];
        *(short8*)&Bs[r * 40 + kq] = *(const short8*)&wrow[k0 + kq];
        __syncthreads();
        short8 a0 = *(const short8*)&As[(wm * 32 + l15) * 40 + q * 8];
        short8 a1 = *(const short8*)&As[(wm * 32 + 16 + l15) * 40 + q * 8];
        short8 b0 = *(const short8*)&Bs[(wn * 32 + l15) * 40 + q * 8];
        short8 b1 = *(const short8*)&Bs[(wn * 32 + 16 + l15) * 40 + q * 8];
        acc[0][0] = __builtin_amdgcn_mfma_f32_16x16x32_bf16(a0, b0, acc[0][0], 0, 0, 0);
        acc[0][1] = __builtin_amdgcn_mfma_f32_16x16x32_bf16(a0, b1, acc[0][1], 0, 0, 0);
        acc[1][0] = __builtin_amdgcn_mfma_f32_16x16x32_bf16(a1, b0, acc[1][0], 0, 0, 0);
        acc[1][1] = __builtin_amdgcn_mfma_f32_16x16x32_bf16(a1, b1, acc[1][1], 0, 0, 0);
        __syncthreads();
    }
    for (int mi = 0; mi < 2; ++mi)
        for (int ni = 0; ni < 2; ++ni) {
            int col = tn * 64 + wn * 32 + ni * 16 + l15;
            float bv = bias[col];
            int row0 = tm * 64 + wm * 32 + mi * 16 + q * 4;
            for (int rr = 0; rr < 4; ++rr) {
                Cout[(size_t)(row0 + rr) * 3072 + col] = f2bf(acc[mi][ni][rr] + bv);
            }
        }
}

// Fused 2-layer persistent GRU, 128 blocks x 512 threads (8 waves).
// R10: weights hoisted into VGPRs (t-invariant; 48 VGPR/lane L0, 96 L1 —
// deletes 24 of 32 per-step VMEM ops from the serial chain); direct export
// (gate thread tid owns ring dword (chunk<<8)+tid; deletes the LDS slice
// stage and one __syncthreads). Blocks 0-63 = L0 (8-way K-split); 64-127 =
// L1 wave-specialized (waves 0-3 h-part, 4-7 x-part on ring0 which L0 keeps
// ahead). Single-wave polling (wv0; wv4 for L1's flags0). Chunked write-once
// rings + plain cached consumer loads + agent-store/vmcnt/flag release.
__global__ __launch_bounds__(512) void gru_fused(
    const unsigned short* __restrict__ gx0, const unsigned short* __restrict__ whh0,
    const float* __restrict__ bhh0, const unsigned short* __restrict__ wih1,
    const unsigned short* __restrict__ whh1, const float* __restrict__ bih1,
    const float* __restrict__ bhh1, unsigned short* __restrict__ ring0,
    unsigned short* __restrict__ ring1, float* __restrict__ hn0,
    float* __restrict__ hn1, unsigned int* __restrict__ flags) {
    __shared__ __align__(16) float red[8 * 6 * 64 * 4];  // 48 KB
    const int bid = blockIdx.x;
    const int tid = threadIdx.x;
    const int lane = tid & 63, wv = tid >> 6;
    const int l15 = lane & 15, q = lane >> 4;
    // gate/export ownership (tid<256): thread -> (b=tid>>3, jh=tid&7),
    // j = 2jh, 2jh+1; its packed dword is ring dword (chunk<<8)+tid.
    const int gb = tid >> 3, gjh = tid & 7;
    const int gmi = gb >> 4, greg = gb & 3;
    const int grl = ((gb & 15) >> 2) * 16 + 2 * gjh;  // MFMA C-layout lane (i=0)

    if (bid < 64) {
        // ================= layer 0 : 8-way K-split, K=128/wave =================
        const int j0 = bid * 16;
        const int kbase = wv * 128;
        // hoist whh0 slice into VGPRs (12 x short8 = 48 VGPR)
        short8 Wr[4], Wz[4], Wn[4];
        {
            const unsigned short* wr0 = whh0 + (size_t)(j0 + l15) * HH;
            const unsigned short* wr1 = whh0 + (size_t)(1024 + j0 + l15) * HH;
            const unsigned short* wr2 = whh0 + (size_t)(2048 + j0 + l15) * HH;
#pragma unroll
            for (int s = 0; s < 4; ++s) {
                int k = kbase + s * 32 + q * 8;
                Wr[s] = *(const short8*)&wr0[k];
                Wz[s] = *(const short8*)&wr1[k];
                Wn[s] = *(const short8*)&wr2[k];
            }
        }
        float bR[2], bZ[2], bN[2], hpriv[2] = {0.f, 0.f};
        unsigned int pxr = 0, pxz = 0, pxn = 0;
        const unsigned short* gxp = nullptr;
        if (tid < 256) {
            int jj = j0 + 2 * gjh;
#pragma unroll
            for (int i = 0; i < 2; ++i) {
                bR[i] = bhh0[jj + i];
                bZ[i] = bhh0[1024 + jj + i];
                bN[i] = bhh0[2048 + jj + i];
            }
            gxp = gx0 + (size_t)gb * TT * 3072 + jj;
            pxr = *(const unsigned int*)(gxp);
            pxz = *(const unsigned int*)(gxp + 1024);
            pxn = *(const unsigned int*)(gxp + 2048);
        }

        for (int t = 0; t < TT; ++t) {
            if (t > 0 && wv == 0) {
                unsigned int target = (unsigned int)t;
                while (true) {
                    unsigned int v = __hip_atomic_load(flags + lane, __ATOMIC_RELAXED,
                                                       __HIP_MEMORY_SCOPE_AGENT);
                    if (__all((int)(v >= target))) break;
                    __builtin_amdgcn_s_sleep(1);
                }
            }
            __syncthreads();
            const unsigned short* hc = ring0 + (size_t)t * SLOT;
            unsigned int cxr = pxr, cxz = pxz, cxn = pxn;

            floatx4 acc[6] = {};
#pragma unroll
            for (int s = 0; s < 4; ++s) {
                int k = kbase + s * 32 + q * 8;
                int cb = (k >> 4) << 9, ko = k & 15;
                short8 a0 = *(const short8*)&hc[cb + (l15 << 4) + ko];
                short8 a1 = *(const short8*)&hc[cb + ((16 + l15) << 4) + ko];
                acc[0] = __builtin_amdgcn_mfma_f32_16x16x32_bf16(a0, Wr[s], acc[0], 0, 0, 0);
                acc[1] = __builtin_amdgcn_mfma_f32_16x16x32_bf16(a0, Wz[s], acc[1], 0, 0, 0);
                acc[2] = __builtin_amdgcn_mfma_f32_16x16x32_bf16(a0, Wn[s], acc[2], 0, 0, 0);
                acc[3] = __builtin_amdgcn_mfma_f32_16x16x32_bf16(a1, Wr[s], acc[3], 0, 0, 0);
                acc[4] = __builtin_amdgcn_mfma_f32_16x16x32_bf16(a1, Wz[s], acc[4], 0, 0, 0);
                acc[5] = __builtin_amdgcn_mfma_f32_16x16x32_bf16(a1, Wn[s], acc[5], 0, 0, 0);
            }
#pragma unroll
            for (int tl = 0; tl < 6; ++tl)
                *(floatx4*)&red[((wv * 6 + tl) * 64 + lane) * 4] = acc[tl];
            __syncthreads();

            float hnew[2];
            if (tid < 256) {
#pragma unroll
                for (int i = 0; i < 2; ++i) {
                    int rl = grl + i;
                    float gr = 0.f, gz = 0.f, gn = 0.f;
#pragma unroll
                    for (int w = 0; w < 8; ++w) {
                        gr += red[((w * 6 + gmi * 3 + 0) * 64 + rl) * 4 + greg];
                        gz += red[((w * 6 + gmi * 3 + 1) * 64 + rl) * 4 + greg];
                        gn += red[((w * 6 + gmi * 3 + 2) * 64 + rl) * 4 + greg];
                    }
                    float xr = bf2f((unsigned short)(i ? (cxr >> 16) : (cxr & 0xffffu)));
                    float xz = bf2f((unsigned short)(i ? (cxz >> 16) : (cxz & 0xffffu)));
                    float xn = bf2f((unsigned short)(i ? (cxn >> 16) : (cxn & 0xffffu)));
                    float rg = 1.f / (1.f + __expf(-(xr + gr + bR[i])));
                    float zg = 1.f / (1.f + __expf(-(xz + gz + bZ[i])));
                    float ng = tanhf(xn + rg * (gn + bN[i]));
                    hnew[i] = (1.f - zg) * ng + zg * hpriv[i];
                    hpriv[i] = hnew[i];
                }
                unsigned int hpack =
                    (unsigned int)f2bf(hnew[0]) | ((unsigned int)f2bf(hnew[1]) << 16);
                unsigned int* dst =
                    (unsigned int*)(ring0 + (size_t)(t + 1) * SLOT) + (bid << 8) + tid;
                __hip_atomic_store(dst, hpack, __ATOMIC_RELAXED,
                                   __HIP_MEMORY_SCOPE_AGENT);
                asm volatile("s_waitcnt vmcnt(0)" ::: "memory");
            }
            __syncthreads();
            if (tid == 0)
                __hip_atomic_store(flags + bid, (unsigned int)(t + 1), __ATOMIC_RELAXED,
                                   __HIP_MEMORY_SCOPE_AGENT);
            if (tid < 256) {
                if (t == TT - 1) {
                    hn0[gb * HH + j0 + 2 * gjh] = hnew[0];
                    hn0[gb * HH + j0 + 2 * gjh + 1] = hnew[1];
                }
                if (t + 1 < TT) {
                    const unsigned short* g2 = gxp + (size_t)(t + 1) * 3072;
                    pxr = *(const unsigned int*)(g2);
                    pxz = *(const unsigned int*)(g2 + 1024);
                    pxn = *(const unsigned int*)(g2 + 2048);
                }
            }
        }
    } else {
        // ===== layer 1 : wave-specialized (waves 0-3 h / whh1, 4-7 x / wih1) =====
        const int b2 = bid - 64;
        const int j0 = b2 * 16;
        const bool isx = (wv >= 4);
        const int kbase = (wv & 3) * 256;
        // hoist weight slice into VGPRs (24 x short8 = 96 VGPR)
        short8 Wr[8], Wz[8], Wn[8];
        {
            const unsigned short* wsrc = isx ? wih1 : whh1;
            const unsigned short* w0 = wsrc + (size_t)(j0 + l15) * HH;
            const unsigned short* w1 = wsrc + (size_t)(1024 + j0 + l15) * HH;
            const unsigned short* w2 = wsrc + (size_t)(2048 + j0 + l15) * HH;
#pragma unroll
            for (int s = 0; s < 8; ++s) {
                int k = kbase + s * 32 + q * 8;
                Wr[s] = *(const short8*)&w0[k];
                Wz[s] = *(const short8*)&w1[k];
                Wn[s] = *(const short8*)&w2[k];
            }
        }
        float cR[2], cZ[2], cNx[2], cNh[2], hpriv[2] = {0.f, 0.f};
        if (tid < 256) {
            int jj = j0 + 2 * gjh;
#pragma unroll
            for (int i = 0; i < 2; ++i) {
                cR[i] = bih1[jj + i] + bhh1[jj + i];
                cZ[i] = bih1[1024 + jj + i] + bhh1[1024 + jj + i];
                cNx[i] = bih1[2048 + jj + i];
                cNh[i] = bhh1[2048 + jj + i];
            }
        }

        for (int t = 0; t < TT; ++t) {
            if (t > 0 && wv == 0) {  // own-layer flags (ring1 critical path)
                unsigned int target = (unsigned int)t;
                while (true) {
                    unsigned int v = __hip_atomic_load(flags + 64 + lane,
                                                       __ATOMIC_RELAXED,
                                                       __HIP_MEMORY_SCOPE_AGENT);
                    if (__all((int)(v >= target))) break;
                    __builtin_amdgcn_s_sleep(1);
                }
            }
            if (wv == 4) {  // L0 flags for h0(t) = ring0 slot t+1 (runs ahead)
                unsigned int target = (unsigned int)(t + 1);
                while (true) {
                    unsigned int v = __hip_atomic_load(flags + lane, __ATOMIC_RELAXED,
                                                       __HIP_MEMORY_SCOPE_AGENT);
                    if (__all((int)(v >= target))) break;
                    __builtin_amdgcn_s_sleep(1);
                }
            }
            __syncthreads();
            const unsigned short* src =
                isx ? (ring0 + (size_t)(t + 1) * SLOT) : (ring1 + (size_t)t * SLOT);

            floatx4 acc[6] = {};
#pragma unroll
            for (int s = 0; s < 8; ++s) {
                int k = kbase + s * 32 + q * 8;
                int cb = (k >> 4) << 9, ko = k & 15;
                short8 a0 = *(const short8*)&src[cb + (l15 << 4) + ko];
                short8 a1 = *(const short8*)&src[cb + ((16 + l15) << 4) + ko];
                acc[0] = __builtin_amdgcn_mfma_f32_16x16x32_bf16(a0, Wr[s], acc[0], 0, 0, 0);
                acc[1] = __builtin_amdgcn_mfma_f32_16x16x32_bf16(a0, Wz[s], acc[1], 0, 0, 0);
                acc[2] = __builtin_amdgcn_mfma_f32_16x16x32_bf16(a0, Wn[s], acc[2], 0, 0, 0);
                acc[3] = __builtin_amdgcn_mfma_f32_16x16x32_bf16(a1, Wr[s], acc[3], 0, 0, 0);
                acc[4] = __builtin_amdgcn_mfma_f32_16x16x32_bf16(a1, Wz[s], acc[4], 0, 0, 0);
                acc[5] = __builtin_amdgcn_mfma_f32_16x16x32_bf16(a1, Wn[s], acc[5], 0, 0, 0);
            }
#pragma unroll
            for (int tl = 0; tl < 6; ++tl)
                *(floatx4*)&red[((wv * 6 + tl) * 64 + lane) * 4] = acc[tl];
            __syncthreads();

            float hnew[2];
            if (tid < 256) {
#pragma unroll
                for (int i = 0; i < 2; ++i) {
                    int rl = grl + i;
                    float gr = 0.f, gz = 0.f, hn = 0.f, xn = 0.f;
#pragma unroll
                    for (int w = 0; w < 4; ++w) {
                        gr += red[((w * 6 + gmi * 3 + 0) * 64 + rl) * 4 + greg];
                        gz += red[((w * 6 + gmi * 3 + 1) * 64 + rl) * 4 + greg];
                        hn += red[((w * 6 + gmi * 3 + 2) * 64 + rl) * 4 + greg];
                    }
#pragma unroll
                    for (int w = 4; w < 8; ++w) {
                        gr += red[((w * 6 + gmi * 3 + 0) * 64 + rl) * 4 + greg];
                        gz += red[((w * 6 + gmi * 3 + 1) * 64 + rl) * 4 + greg];
                        xn += red[((w * 6 + gmi * 3 + 2) * 64 + rl) * 4 + greg];
                    }
                    float rg = 1.f / (1.f + __expf(-(gr + cR[i])));
                    float zg = 1.f / (1.f + __expf(-(gz + cZ[i])));
                    float ng = tanhf(xn + cNx[i] + rg * (hn + cNh[i]));
                    hnew[i] = (1.f - zg) * ng + zg * hpriv[i];
                    hpriv[i] = hnew[i];
                }
                unsigned int hpack =
                    (unsigned int)f2bf(hnew[0]) | ((unsigned int)f2bf(hnew[1]) << 16);
                unsigned int* dst =
                    (unsigned int*)(ring1 + (size_t)(t + 1) * SLOT) + (b2 << 8) + tid;
                __hip_atomic_store(dst, hpack, __ATOMIC_RELAXED,
                                   __HIP_MEMORY_SCOPE_AGENT);
                asm volatile("s_waitcnt vmcnt(0)" ::: "memory");
            }
            __syncthreads();
            if (tid == 0)
                __hip_atomic_store(flags + 64 + b2, (unsigned int)(t + 1),
                                   __ATOMIC_RELAXED, __HIP_MEMORY_SCOPE_AGENT);
            if (tid < 256 && t == TT - 1) {
                hn1[gb * HH + j0 + 2 * gjh] = hnew[0];
                hn1[gb * HH + j0 + 2 * gjh + 1] = hnew[1];
            }
        }
    }
}

// h1bf is ring1 slot TT in chunked layout: (b,k) at (k>>4)*512 + b*16 + (k&15)
__global__ void fc_out(const unsigned short* __restrict__ h1bf,
                       const float* __restrict__ fcw, const float* __restrict__ fcb,
                       float* __restrict__ out) {
    int b = blockIdx.x, o = threadIdx.x;  // 32 x 256
    const float* wr = fcw + (size_t)o * HH;
    float acc = fcb[o];
    for (int k = 0; k < HH; k += 16) {
        const unsigned short* hp = h1bf + ((k >> 4) << 9) + (b << 4);
#pragma unroll
        for (int i = 0; i < 16; ++i) acc += bf2f(hp[i]) * wr[k + i];
    }
    out[b * OUTW + o] = 1.f / (1.f + expf(-acc));
}

extern "C" void kernel_launch(void* const* d_in, const int* in_sizes, int n_in,
                              void* d_out, int out_size, void* d_ws, size_t ws_size,
                              hipStream_t stream) {
    (void)in_sizes; (void)n_in; (void)out_size; (void)ws_size;
    const float* input = (const float*)d_in[0];
    const float* w_ih0 = (const float*)d_in[1];
    const float* w_hh0 = (const float*)d_in[2];
    const float* b_ih0 = (const float*)d_in[3];
    const float* b_hh0 = (const float*)d_in[4];
    const float* w_ih1 = (const float*)d_in[5];
    const float* w_hh1 = (const float*)d_in[6];
    const float* b_ih1 = (const float*)d_in[7];
    const float* b_hh1 = (const float*)d_in[8];
    const float* fc_w = (const float*)d_in[9];
    const float* fc_b = (const float*)d_in[10];
    float* out = (float*)d_out;

    char* ws = (char*)d_ws;
    size_t off = 0;
    auto alloc = [&](size_t bytes) {
        void* p = ws + off;
        off += (bytes + 255) & ~(size_t)255;
        return p;
    };
    unsigned int* flags = (unsigned int*)alloc(4096);  // L0: [0..64), L1: [64..128)
    unsigned short* ring0 = (unsigned short*)alloc((size_t)(TT + 1) * SLOT * 2);
    unsigned short* ring1 = (unsigned short*)alloc((size_t)(TT + 1) * SLOT * 2);
    unsigned short* gx0 = (unsigned short*)alloc((size_t)16384 * 3072 * 2);
    unsigned short* in_bf = (unsigned short*)alloc((size_t)16384 * 256 * 2);
    unsigned short* wih0_bf = (unsigned short*)alloc((size_t)3072 * 256 * 2);
    unsigned short* whh0_bf = (unsigned short*)alloc((size_t)3072 * 1024 * 2);
    unsigned short* wih1_bf = (unsigned short*)alloc((size_t)3072 * 1024 * 2);
    unsigned short* whh1_bf = (unsigned short*)alloc((size_t)3072 * 1024 * 2);

    cast_f32_bf16<<<256, 256, 0, stream>>>(input, in_bf, 16384 * 256);
    cast_f32_bf16<<<64, 256, 0, stream>>>(w_ih0, wih0_bf, 3072 * 256);
    cast_f32_bf16<<<256, 256, 0, stream>>>(w_hh0, whh0_bf, 3072 * 1024);
    cast_f32_bf16<<<256, 256, 0, stream>>>(w_ih1, wih1_bf, 3072 * 1024);
    cast_f32_bf16<<<256, 256, 0, stream>>>(w_hh1, whh1_bf, 3072 * 1024);

    hipMemsetAsync(flags, 0, 4096, stream);
    hipMemsetAsync(ring0, 0, (size_t)SLOT * 2, stream);  // h0(0) = 0
    hipMemsetAsync(ring1, 0, (size_t)SLOT * 2, stream);  // h1(0) = 0

    // gx0 = input @ w_ih0^T + b_ih0 (layer-1 projections fused into gru kernel)
    gemm_gx<256><<<12288, 256, 0, stream>>>(in_bf, wih0_bf, b_ih0, gx0);

    gru_fused<<<128, 512, 0, stream>>>(gx0, whh0_bf, b_hh0, wih1_bf, whh1_bf, b_ih1,
                                       b_hh1, ring0, ring1, out + 8192,
                                       out + 8192 + 32768, flags);

    // ---- FC + sigmoid on h_last of layer 1 (ring1 slot TT, chunked) ----
    fc_out<<<32, 256, 0, stream>>>(ring1 + (size_t)TT * SLOT, fc_w, fc_b, out);
}